// Round 2
// baseline (464.195 us; speedup 1.0000x reference)
//
#include <hip/hip_runtime.h>
#include <hip/hip_bf16.h>
#include <math.h>

#define NTOK   16384
#define DM     768
#define DF     3072
#define NEXP   4

// prep kernel flat-grid section sizes
#define XBLKS  6144                    // (NTOK*DM)/(256*8)
#define W1BLKS 2304                    // 4 * (DF/64) * (DM/64) = 4*48*12
#define W2BLKS 2304                    // 4 * (DM/64) * (DF/64)
#define PREP_BLKS (1 + XBLKS + W1BLKS + W2BLKS)

#define MAXP   68                      // max 256-row panels: 16384/256 + 4

typedef short bf16x8 __attribute__((ext_vector_type(8)));
typedef float f32x4  __attribute__((ext_vector_type(4)));

// ---------------- workspace layout (bytes) ----------------
#define WS_CNT    0u
#define WS_BASES  256u                        // bases[4] + panel offsets (ints)
#define WS_POS    512u                        // NTOK ints            = 65536
#define WS_LIST   (512u + 65536u)             // NEXP*NTOK ints       = 262144
#define WS_XB     (WS_LIST + 262144u)         // NTOK*DM bf16         = 25165824
#define WS_W1T    (WS_XB + 25165824u)         // 4*DF*DM bf16         = 18874368
#define WS_W2T    (WS_W1T + 18874368u)        // 4*DM*DF bf16         = 18874368
#define WS_H1     (WS_W2T + 18874368u)        // NTOK*DF bf16         = 100663296
#define WS_H2     (WS_H1 + 100663296u)        // NTOK*DM bf16         = 25165824
#define WS_END    (WS_H2 + 25165824u)

// ---------------- bf16 helpers (manual, RNE) ----------------
__device__ __forceinline__ ushort f2bf(float f) {
    unsigned int v; __builtin_memcpy(&v, &f, 4);
    v = v + 0x7fffu + ((v >> 16) & 1u);
    return (ushort)(v >> 16);
}
__device__ __forceinline__ float bf2f(ushort u) {
    unsigned int v = ((unsigned int)u) << 16;
    float f; __builtin_memcpy(&f, &v, 4); return f;
}

// fast gelu: x * sigmoid(1.5957691(x + 0.044715 x^3)); exp2-based, ~1e-3 abs err
__device__ __forceinline__ float fast_gelu(float v) {
    float y = v + 0.044715f * v * v * v;
    float e = __builtin_amdgcn_exp2f(-2.3022082f * y);
    return v * __builtin_amdgcn_rcpf(1.0f + e);
}

// async global->LDS, 16B per lane. LDS dest must be uniform_base + lane*16.
typedef __attribute__((address_space(1))) const void gvoid_t;
typedef __attribute__((address_space(3))) void lvoid_t;
__device__ __forceinline__ void cp16(const void* g, void* l) {
    __builtin_amdgcn_global_load_lds((gvoid_t*)g, (lvoid_t*)l, 16, 0, 0);
}

// bijective chunked XCD remap over T active blocks (m204 formula)
__device__ __forceinline__ int xcd_remap(int id, int T) {
    const int q = T >> 3, r = T & 7;
    const int x = id & 7, j = id >> 3;
    return (x < r ? x * (q + 1) : r * (q + 1) + (x - r) * q) + j;
}

// ---------------- transpose tile helper ----------------
__device__ __forceinline__ void transpose_tile(
    const float* __restrict__ src, ushort* __restrict__ dst, int R, int C,
    int bx, int by, int tid, ushort* tile /* [64][72] */) {
    const int r0 = by * 64, c0 = bx * 64;
#pragma unroll
    for (int q = 0; q < 2; ++q) {
        int li = q * 256 + tid;
        int r = li >> 3, c = (li & 7) * 8;
        const float* s = src + (size_t)(r0 + r) * C + (c0 + c);
        float4 v0 = *(const float4*)s;
        float4 v1 = *(const float4*)(s + 4);
        ushort tmp[8];
        tmp[0] = f2bf(v0.x); tmp[1] = f2bf(v0.y); tmp[2] = f2bf(v0.z); tmp[3] = f2bf(v0.w);
        tmp[4] = f2bf(v1.x); tmp[5] = f2bf(v1.y); tmp[6] = f2bf(v1.z); tmp[7] = f2bf(v1.w);
        int sw = (((c >> 3) ^ ((r >> 3) & 7)) << 3);
        *(uint4*)&tile[r * 72 + sw] = *(uint4*)tmp;
    }
    __syncthreads();
#pragma unroll
    for (int q = 0; q < 2; ++q) {
        int li = q * 256 + tid;
        int r = li >> 3, c = (li & 7) * 8;
        ushort tmp[8];
#pragma unroll
        for (int j = 0; j < 8; ++j)
            tmp[j] = tile[(c + j) * 72 +
                          ((((r >> 3) & 7) ^ (((c + j) >> 3) & 7)) << 3) + (r & 7)];
        *(uint4*)(dst + (size_t)(c0 + r) * R + (r0 + c)) = *(uint4*)tmp;
    }
}

// ---------------- prep: routing + X cvt + W1/W2 transpose ----------------
__global__ __launch_bounds__(256) void prep_kernel(
    const int* __restrict__ type_seq, const float* __restrict__ X,
    const float* __restrict__ W1, const float* __restrict__ W2,
    int* __restrict__ cnt, int* __restrict__ bases,
    int* __restrict__ pos_of, int* __restrict__ list,
    ushort* __restrict__ Xb, ushort* __restrict__ W1t, ushort* __restrict__ W2t) {
    __shared__ ushort tile[64 * 72];
    __shared__ int lcnt[NEXP];
    const int tid = threadIdx.x;
    const int bid = blockIdx.x;

    if (bid == 0) {
        if (tid < NEXP) lcnt[tid] = 0;
        __syncthreads();
        const int lane = tid & 63;
        for (int it = 0; it < NTOK / 256; ++it) {
            int t = it * 256 + tid;
            int k = type_seq[t];
#pragma unroll
            for (int e = 0; e < NEXP; ++e) {
                unsigned long long m = __ballot(k == e + 1);
                int total = __popcll(m);
                int b = 0;
                if (lane == 0 && total) b = atomicAdd(&lcnt[e], total);
                b = __shfl(b, 0, 64);
                if (k == e + 1) {
                    int p = b + __popcll(m & ((1ull << lane) - 1ull));
                    list[e * NTOK + p] = t;
                    pos_of[t] = p;
                }
            }
        }
        __syncthreads();
        if (tid == 0) {
            int s = 0, mb = 0;
            for (int e = 0; e < NEXP; ++e) {
                cnt[e] = lcnt[e];
                bases[e] = s;
                bases[8 + e] = mb;                 // 256-row panel offsets
                s += lcnt[e];
                mb += (lcnt[e] + 255) >> 8;
            }
            bases[12] = mb;
        }
        return;
    }

    int id = bid - 1;
    if (id < XBLKS) {
        size_t i = (size_t)(id * 256 + tid) * 8;
        float4 v0 = *(const float4*)(X + i);
        float4 v1 = *(const float4*)(X + i + 4);
        ushort tmp[8];
        tmp[0] = f2bf(v0.x); tmp[1] = f2bf(v0.y); tmp[2] = f2bf(v0.z); tmp[3] = f2bf(v0.w);
        tmp[4] = f2bf(v1.x); tmp[5] = f2bf(v1.y); tmp[6] = f2bf(v1.z); tmp[7] = f2bf(v1.w);
        *(uint4*)(Xb + i) = *(uint4*)tmp;
        return;
    }
    id -= XBLKS;
    if (id < W1BLKS) {
        int z = id / 576, r = id % 576;
        size_t mb = (size_t)z * DM * DF;
        transpose_tile(W1 + mb, W1t + mb, DM, DF, r % 48, r / 48, tid, tile);
        return;
    }
    id -= W1BLKS;
    {
        int z = id / 576, r = id % 576;
        size_t mb = (size_t)z * DF * DM;
        transpose_tile(W2 + mb, W2t + mb, DF, DM, r % 12, r / 12, tid, tile);
    }
}

// =====================================================================
// GEMM template (both kernels): 512 threads = 8 waves (2M x 4N), tile
// 256x256, BK=64, per-wave 128x64 output (8x4 f32x4 acc = 128 AGPR).
// Depth-2 prefetch, counted vmcnt(8) across barriers (T3+T4), setprio
// around 2nd MFMA cluster (T5), k-quad XOR swizzle key=row&7 (T2,
// both-sides: pre-swizzled global source + swizzled ds_read offset).
// Per K-step: 24 ds_read_b128, 64 MFMA, 8 cp16. LDS 128 KiB, 1 blk/CU.
// =====================================================================

__global__ __launch_bounds__(512, 2) void gemm1_kernel(
    const ushort* __restrict__ Xb, const ushort* __restrict__ W1t,
    const float* __restrict__ b1, const int* __restrict__ cnt,
    const int* __restrict__ bases, const int* __restrict__ list,
    ushort* __restrict__ h1) {
    const int mb = bases[12];
    const int T = mb * 12;
    int id = blockIdx.y * 12 + blockIdx.x;
    if (id >= T) return;
    id = xcd_remap(id, T);
    const int y = id / 12;
    const int n0 = (id % 12) * 256;
    const int* mboff = bases + 8;
    const int e = (y >= mboff[1]) + (y >= mboff[2]) + (y >= mboff[3]);
    const int m0 = (y - mboff[e]) << 8;
    const int count = cnt[e];
    const int base = bases[e];

    __shared__ __align__(16) short As[2][16384];
    __shared__ __align__(16) short Bs[2][16384];

    const int tid = threadIdx.x;
    const int wave = tid >> 6, lane = tid & 63;
    const int wr = wave >> 2, wc = wave & 3;
    const int lrow = lane & 15, qg = lane >> 4;

    // ---- staging setup: thread stages rows rbase+64s, quad tid&7 ----
    const int rbase = tid >> 3;
    const int qsrc = ((tid & 7) ^ (rbase & 7)) * 8;   // source k-quad pre-swizzle
    const ushort* aP[4];
#pragma unroll
    for (int s = 0; s < 4; ++s) {
        int r = min(m0 + rbase + s * 64, count - 1);
        aP[s] = Xb + (size_t)list[e * NTOK + r] * DM + qsrc;
    }
    const ushort* Wb = W1t + (size_t)e * DF * DM;
    const ushort* bP = Wb + (size_t)(n0 + rbase) * DM + qsrc;

    // ---- fragment read offsets (kh=0; kh=1 = ^32 shorts) ----
    int aOff[8], bOff[4];
#pragma unroll
    for (int i = 0; i < 8; ++i) {
        int r = wr * 128 + i * 16 + lrow;
        aOff[i] = r * 64 + (qg ^ (lrow & 7)) * 8;
    }
#pragma unroll
    for (int j = 0; j < 4; ++j) {
        int r = wc * 64 + j * 16 + lrow;
        bOff[j] = r * 64 + (qg ^ (lrow & 7)) * 8;
    }

    f32x4 acc[8][4];
    f32x4 zz = {0.f, 0.f, 0.f, 0.f};
#pragma unroll
    for (int i = 0; i < 8; ++i)
#pragma unroll
        for (int j = 0; j < 4; ++j) acc[i][j] = zz;

    auto STAGE = [&](int buf) {
        short* aD = &As[buf][0] + tid * 8;
        short* bD = &Bs[buf][0] + tid * 8;
#pragma unroll
        for (int s = 0; s < 4; ++s) { cp16(aP[s], aD + s * 4096); aP[s] += 64; }
#pragma unroll
        for (int s = 0; s < 4; ++s) cp16(bP + (size_t)s * 64 * DM, bD + s * 4096);
        bP += 64;
    };

    STAGE(0); STAGE(1);                       // 16 cp16 in flight
    asm volatile("s_waitcnt vmcnt(8)" ::: "memory");   // tile0 landed
    __builtin_amdgcn_s_barrier();

    const int NK = DM / 64;                   // 12
    for (int ks = 0; ks < NK; ++ks) {
        const short* Ab = &As[ks & 1][0];
        const short* Bb = &Bs[ks & 1][0];
        // sub-phase kh=0
        bf16x8 a0[8], b0[4];
#pragma unroll
        for (int i = 0; i < 8; ++i) a0[i] = *(const bf16x8*)(Ab + aOff[i]);
#pragma unroll
        for (int j = 0; j < 4; ++j) b0[j] = *(const bf16x8*)(Bb + bOff[j]);
#pragma unroll
        for (int i = 0; i < 8; ++i)
#pragma unroll
            for (int j = 0; j < 4; ++j)
                acc[i][j] = __builtin_amdgcn_mfma_f32_16x16x32_bf16(a0[i], b0[j], acc[i][j], 0, 0, 0);
        // sub-phase kh=1 reads
        bf16x8 a1[8], b1v[4];
#pragma unroll
        for (int i = 0; i < 8; ++i) a1[i] = *(const bf16x8*)(Ab + (aOff[i] ^ 32));
#pragma unroll
        for (int j = 0; j < 4; ++j) b1v[j] = *(const bf16x8*)(Bb + (bOff[j] ^ 32));
        asm volatile("s_waitcnt lgkmcnt(0)" ::: "memory");   // all reads of buf done
        __builtin_amdgcn_sched_barrier(0);
        __builtin_amdgcn_s_barrier();                         // safe to restage buf
        if (ks + 2 < NK) STAGE(ks & 1);                       // tile ks+2 -> buf[ks&1]
        __builtin_amdgcn_s_setprio(1);
#pragma unroll
        for (int i = 0; i < 8; ++i)
#pragma unroll
            for (int j = 0; j < 4; ++j)
                acc[i][j] = __builtin_amdgcn_mfma_f32_16x16x32_bf16(a1[i], b1v[j], acc[i][j], 0, 0, 0);
        __builtin_amdgcn_s_setprio(0);
        __builtin_amdgcn_sched_barrier(0);
        if (ks + 2 < NK) { asm volatile("s_waitcnt vmcnt(8)" ::: "memory"); }
        else             { asm volatile("s_waitcnt vmcnt(0)" ::: "memory"); }
        __builtin_amdgcn_s_barrier();                         // tile ks+1 published
    }

    // epilogue: bias + gelu + store
    float bias[4];
#pragma unroll
    for (int j = 0; j < 4; ++j) bias[j] = b1[e * DF + n0 + wc * 64 + j * 16 + lrow];
#pragma unroll
    for (int i = 0; i < 8; ++i) {
        int gm = m0 + wr * 128 + i * 16 + qg * 4;
#pragma unroll
        for (int j = 0; j < 4; ++j) {
            int gn = n0 + wc * 64 + j * 16 + lrow;
#pragma unroll
            for (int r = 0; r < 4; ++r) {
                int row = gm + r;
                if (row < count)
                    h1[(size_t)(base + row) * DF + gn] = f2bf(fast_gelu(acc[i][j][r] + bias[j]));
            }
        }
    }
}

__global__ __launch_bounds__(512, 2) void gemm2_kernel(
    const ushort* __restrict__ h1, const ushort* __restrict__ W2t,
    const float* __restrict__ b2, const int* __restrict__ cnt,
    const int* __restrict__ bases, ushort* __restrict__ h2) {
    const int mb = bases[12];
    const int T = mb * 3;
    int id = blockIdx.y * 3 + blockIdx.x;
    if (id >= T) return;
    id = xcd_remap(id, T);
    const int y = id / 3;
    const int n0 = (id % 3) * 256;
    const int* mboff = bases + 8;
    const int e = (y >= mboff[1]) + (y >= mboff[2]) + (y >= mboff[3]);
    const int m0 = (y - mboff[e]) << 8;
    const int count = cnt[e];
    const int base = bases[e];

    __shared__ __align__(16) short As[2][16384];
    __shared__ __align__(16) short Bs[2][16384];

    const int tid = threadIdx.x;
    const int wave = tid >> 6, lane = tid & 63;
    const int wr = wave >> 2, wc = wave & 3;
    const int lrow = lane & 15, qg = lane >> 4;

    const int rbase = tid >> 3;
    const int qsrc = ((tid & 7) ^ (rbase & 7)) * 8;
    const ushort* aP[4];
#pragma unroll
    for (int s = 0; s < 4; ++s) {
        int r = min(m0 + rbase + s * 64, count - 1);
        aP[s] = h1 + (size_t)(base + r) * DF + qsrc;
    }
    const ushort* Wb = W2t + (size_t)e * DM * DF;
    const ushort* bP = Wb + (size_t)(n0 + rbase) * DF + qsrc;

    int aOff[8], bOff[4];
#pragma unroll
    for (int i = 0; i < 8; ++i) {
        int r = wr * 128 + i * 16 + lrow;
        aOff[i] = r * 64 + (qg ^ (lrow & 7)) * 8;
    }
#pragma unroll
    for (int j = 0; j < 4; ++j) {
        int r = wc * 64 + j * 16 + lrow;
        bOff[j] = r * 64 + (qg ^ (lrow & 7)) * 8;
    }

    f32x4 acc[8][4];
    f32x4 zz = {0.f, 0.f, 0.f, 0.f};
#pragma unroll
    for (int i = 0; i < 8; ++i)
#pragma unroll
        for (int j = 0; j < 4; ++j) acc[i][j] = zz;

    auto STAGE = [&](int buf) {
        short* aD = &As[buf][0] + tid * 8;
        short* bD = &Bs[buf][0] + tid * 8;
#pragma unroll
        for (int s = 0; s < 4; ++s) { cp16(aP[s], aD + s * 4096); aP[s] += 64; }
#pragma unroll
        for (int s = 0; s < 4; ++s) cp16(bP + (size_t)s * 64 * DF, bD + s * 4096);
        bP += 64;
    };

    STAGE(0); STAGE(1);
    asm volatile("s_waitcnt vmcnt(8)" ::: "memory");
    __builtin_amdgcn_s_barrier();

    const int NK = DF / 64;                   // 48
    for (int ks = 0; ks < NK; ++ks) {
        const short* Ab = &As[ks & 1][0];
        const short* Bb = &Bs[ks & 1][0];
        bf16x8 a0[8], b0[4];
#pragma unroll
        for (int i = 0; i < 8; ++i) a0[i] = *(const bf16x8*)(Ab + aOff[i]);
#pragma unroll
        for (int j = 0; j < 4; ++j) b0[j] = *(const bf16x8*)(Bb + bOff[j]);
#pragma unroll
        for (int i = 0; i < 8; ++i)
#pragma unroll
            for (int j = 0; j < 4; ++j)
                acc[i][j] = __builtin_amdgcn_mfma_f32_16x16x32_bf16(a0[i], b0[j], acc[i][j], 0, 0, 0);
        bf16x8 a1[8], b1v[4];
#pragma unroll
        for (int i = 0; i < 8; ++i) a1[i] = *(const bf16x8*)(Ab + (aOff[i] ^ 32));
#pragma unroll
        for (int j = 0; j < 4; ++j) b1v[j] = *(const bf16x8*)(Bb + (bOff[j] ^ 32));
        asm volatile("s_waitcnt lgkmcnt(0)" ::: "memory");
        __builtin_amdgcn_sched_barrier(0);
        __builtin_amdgcn_s_barrier();
        if (ks + 2 < NK) STAGE(ks & 1);
        __builtin_amdgcn_s_setprio(1);
#pragma unroll
        for (int i = 0; i < 8; ++i)
#pragma unroll
            for (int j = 0; j < 4; ++j)
                acc[i][j] = __builtin_amdgcn_mfma_f32_16x16x32_bf16(a1[i], b1v[j], acc[i][j], 0, 0, 0);
        __builtin_amdgcn_s_setprio(0);
        __builtin_amdgcn_sched_barrier(0);
        if (ks + 2 < NK) { asm volatile("s_waitcnt vmcnt(8)" ::: "memory"); }
        else             { asm volatile("s_waitcnt vmcnt(0)" ::: "memory"); }
        __builtin_amdgcn_s_barrier();
    }

    float bias[4];
#pragma unroll
    for (int j = 0; j < 4; ++j) bias[j] = b2[e * DM + n0 + wc * 64 + j * 16 + lrow];
#pragma unroll
    for (int i = 0; i < 8; ++i) {
        int gm = m0 + wr * 128 + i * 16 + qg * 4;
#pragma unroll
        for (int j = 0; j < 4; ++j) {
            int gn = n0 + wc * 64 + j * 16 + lrow;
#pragma unroll
            for (int r = 0; r < 4; ++r) {
                int row = gm + r;
                if (row < count)
                    h2[(size_t)(base + row) * DM + gn] = f2bf(acc[i][j][r] + bias[j]);
            }
        }
    }
}

// ---------------- finalize ----------------
__device__ __forceinline__ void block_reduce2(float& a, float& b, float* sm, int tid) {
    __syncthreads();
#pragma unroll
    for (int off = 32; off > 0; off >>= 1) {
        a += __shfl_down(a, off, 64);
        b += __shfl_down(b, off, 64);
    }
    const int wave = tid >> 6, lane = tid & 63;
    if (lane == 0) { sm[wave] = a; sm[4 + wave] = b; }
    __syncthreads();
    a = sm[0] + sm[1] + sm[2] + sm[3];
    b = sm[4] + sm[5] + sm[6] + sm[7];
}

__global__ __launch_bounds__(256) void finalize_kernel(
    const float* __restrict__ X, const int* __restrict__ type_seq,
    const int* __restrict__ pos_of, const int* __restrict__ bases,
    const ushort* __restrict__ h2,
    const float* __restrict__ ln_g, const float* __restrict__ ln_b,
    const float* __restrict__ out_g, const float* __restrict__ out_b,
    float* __restrict__ out) {
    __shared__ float sm[8];
    const int t = blockIdx.x;
    const int tid = threadIdx.x;
    const int k = type_seq[t];

    float xv[3], rv[3];
#pragma unroll
    for (int j = 0; j < 3; ++j) xv[j] = X[(size_t)t * DM + j * 256 + tid];

    if (k > 0) {
        const int e = k - 1;
        const size_t row = (size_t)(bases[e] + pos_of[t]);
        float v[3], s1 = 0.f, s2 = 0.f;
#pragma unroll
        for (int j = 0; j < 3; ++j) {
            v[j] = bf2f(h2[row * DM + j * 256 + tid]) + xv[j];
            s1 += v[j]; s2 += v[j] * v[j];
        }
        block_reduce2(s1, s2, sm, tid);
        float m = s1 * (1.f / DM);
        float inv = rsqrtf(s2 * (1.f / DM) - m * m + 1e-12f);
#pragma unroll
        for (int j = 0; j < 3; ++j) {
            int c = j * 256 + tid;
            rv[j] = (v[j] - m) * inv * ln_g[e * DM + c] + ln_b[e * DM + c];
        }
    } else {
        rv[0] = rv[1] = rv[2] = 0.f;
    }

    float w[3], s1 = 0.f, s2 = 0.f;
#pragma unroll
    for (int j = 0; j < 3; ++j) {
        w[j] = rv[j] + xv[j];
        s1 += w[j]; s2 += w[j] * w[j];
    }
    block_reduce2(s1, s2, sm, tid);
    float m = s1 * (1.f / DM);
    float inv = rsqrtf(s2 * (1.f / DM) - m * m + 1e-12f);
#pragma unroll
    for (int j = 0; j < 3; ++j) {
        int c = j * 256 + tid;
        out[(size_t)t * DM + c] = (w[j] - m) * inv * out_g[c] + out_b[c];
    }
}

// ---------------- launcher ----------------
extern "C" void kernel_launch(void* const* d_in, const int* in_sizes, int n_in,
                              void* d_out, int out_size, void* d_ws, size_t ws_size,
                              hipStream_t stream) {
    if (ws_size < (size_t)WS_END) return;

    const float* X     = (const float*)d_in[0];
    const int*   type  = (const int*)d_in[1];
    const float* W1    = (const float*)d_in[2];
    const float* b1    = (const float*)d_in[3];
    const float* W2    = (const float*)d_in[4];
    const float* b2    = (const float*)d_in[5];
    const float* ln_g  = (const float*)d_in[6];
    const float* ln_b  = (const float*)d_in[7];
    const float* out_g = (const float*)d_in[8];
    const float* out_b = (const float*)d_in[9];
    float* out = (float*)d_out;

    char* ws = (char*)d_ws;
    int* cnt    = (int*)(ws + WS_CNT);
    int* bases  = (int*)(ws + WS_BASES);
    int* pos_of = (int*)(ws + WS_POS);
    int* list   = (int*)(ws + WS_LIST);
    ushort* Xb  = (ushort*)(ws + WS_XB);
    ushort* W1t = (ushort*)(ws + WS_W1T);
    ushort* W2t = (ushort*)(ws + WS_W2T);
    ushort* h1  = (ushort*)(ws + WS_H1);
    ushort* h2  = (ushort*)(ws + WS_H2);

    prep_kernel<<<PREP_BLKS, 256, 0, stream>>>(type, X, W1, W2,
                                               cnt, bases, pos_of, list, Xb, W1t, W2t);
    gemm1_kernel<<<dim3(12, MAXP), 512, 0, stream>>>(Xb, W1t, b1, cnt, bases, list, h1);
    gemm2_kernel<<<dim3(3, MAXP), 512, 0, stream>>>(h1, W2t, b2, cnt, bases, h2);
    finalize_kernel<<<NTOK, 256, 0, stream>>>(X, type, pos_of, bases, h2, ln_g, ln_b, out_g, out_b, out);
}

// Round 3
// 461.958 us; speedup vs baseline: 1.0048x; 1.0048x over previous
//
#include <hip/hip_runtime.h>
#include <hip/hip_bf16.h>
#include <math.h>

#define NTOK   16384
#define DM     768
#define DF     3072
#define NEXP   4

// prep kernel flat-grid section sizes
#define XBLKS  6144                    // (NTOK*DM)/(256*8)
#define W1BLKS 2304                    // 4 * (DF/64) * (DM/64) = 4*48*12
#define W2BLKS 2304                    // 4 * (DM/64) * (DF/64)
#define PREP_BLKS (1 + XBLKS + W1BLKS + W2BLKS)

#define MAXP   132                     // max 128-row panels: 16384/128 + 4

typedef short bf16x8 __attribute__((ext_vector_type(8)));
typedef float f32x4  __attribute__((ext_vector_type(4)));

// ---------------- workspace layout (bytes) ----------------
#define WS_CNT    0u
#define WS_BASES  256u                        // bases[4] + panel offsets (ints)
#define WS_POS    512u                        // NTOK ints            = 65536
#define WS_LIST   (512u + 65536u)             // NEXP*NTOK ints       = 262144
#define WS_XB     (WS_LIST + 262144u)         // NTOK*DM bf16         = 25165824
#define WS_W1T    (WS_XB + 25165824u)         // 4*DF*DM bf16         = 18874368
#define WS_W2T    (WS_W1T + 18874368u)        // 4*DM*DF bf16         = 18874368
#define WS_H1     (WS_W2T + 18874368u)        // NTOK*DF bf16         = 100663296
#define WS_H2     (WS_H1 + 100663296u)        // NTOK*DM bf16         = 25165824
#define WS_END    (WS_H2 + 25165824u)

// ---------------- bf16 helpers (manual, RNE) ----------------
__device__ __forceinline__ ushort f2bf(float f) {
    unsigned int v; __builtin_memcpy(&v, &f, 4);
    v = v + 0x7fffu + ((v >> 16) & 1u);
    return (ushort)(v >> 16);
}
__device__ __forceinline__ float bf2f(ushort u) {
    unsigned int v = ((unsigned int)u) << 16;
    float f; __builtin_memcpy(&f, &v, 4); return f;
}

// fast gelu: x * sigmoid(1.5957691(x + 0.044715 x^3)); exp2-based, ~1e-3 abs err
__device__ __forceinline__ float fast_gelu(float v) {
    float y = v + 0.044715f * v * v * v;
    float e = __builtin_amdgcn_exp2f(-2.3022082f * y);
    return v * __builtin_amdgcn_rcpf(1.0f + e);
}

// async global->LDS, 16B per lane. LDS dest must be uniform_base + lane*16.
typedef __attribute__((address_space(1))) const void gvoid_t;
typedef __attribute__((address_space(3))) void lvoid_t;
__device__ __forceinline__ void cp16(const void* g, void* l) {
    __builtin_amdgcn_global_load_lds((gvoid_t*)g, (lvoid_t*)l, 16, 0, 0);
}

// bijective chunked XCD remap over T active blocks (m204 formula)
__device__ __forceinline__ int xcd_remap(int id, int T) {
    const int q = T >> 3, r = T & 7;
    const int x = id & 7, j = id >> 3;
    return (x < r ? x * (q + 1) : r * (q + 1) + (x - r) * q) + j;
}

// ---------------- transpose tile helper ----------------
__device__ __forceinline__ void transpose_tile(
    const float* __restrict__ src, ushort* __restrict__ dst, int R, int C,
    int bx, int by, int tid, ushort* tile /* [64][72] */) {
    const int r0 = by * 64, c0 = bx * 64;
#pragma unroll
    for (int q = 0; q < 2; ++q) {
        int li = q * 256 + tid;
        int r = li >> 3, c = (li & 7) * 8;
        const float* s = src + (size_t)(r0 + r) * C + (c0 + c);
        float4 v0 = *(const float4*)s;
        float4 v1 = *(const float4*)(s + 4);
        ushort tmp[8];
        tmp[0] = f2bf(v0.x); tmp[1] = f2bf(v0.y); tmp[2] = f2bf(v0.z); tmp[3] = f2bf(v0.w);
        tmp[4] = f2bf(v1.x); tmp[5] = f2bf(v1.y); tmp[6] = f2bf(v1.z); tmp[7] = f2bf(v1.w);
        int sw = (((c >> 3) ^ ((r >> 3) & 7)) << 3);
        *(uint4*)&tile[r * 72 + sw] = *(uint4*)tmp;
    }
    __syncthreads();
#pragma unroll
    for (int q = 0; q < 2; ++q) {
        int li = q * 256 + tid;
        int r = li >> 3, c = (li & 7) * 8;
        ushort tmp[8];
#pragma unroll
        for (int j = 0; j < 8; ++j)
            tmp[j] = tile[(c + j) * 72 +
                          ((((r >> 3) & 7) ^ (((c + j) >> 3) & 7)) << 3) + (r & 7)];
        *(uint4*)(dst + (size_t)(c0 + r) * R + (r0 + c)) = *(uint4*)tmp;
    }
}

// ---------------- prep: routing + X cvt + W1/W2 transpose ----------------
__global__ __launch_bounds__(256) void prep_kernel(
    const int* __restrict__ type_seq, const float* __restrict__ X,
    const float* __restrict__ W1, const float* __restrict__ W2,
    int* __restrict__ cnt, int* __restrict__ bases,
    int* __restrict__ pos_of, int* __restrict__ list,
    ushort* __restrict__ Xb, ushort* __restrict__ W1t, ushort* __restrict__ W2t) {
    __shared__ ushort tile[64 * 72];
    __shared__ int lcnt[NEXP];
    const int tid = threadIdx.x;
    const int bid = blockIdx.x;

    if (bid == 0) {
        if (tid < NEXP) lcnt[tid] = 0;
        __syncthreads();
        const int lane = tid & 63;
        for (int it = 0; it < NTOK / 256; ++it) {
            int t = it * 256 + tid;
            int k = type_seq[t];
#pragma unroll
            for (int e = 0; e < NEXP; ++e) {
                unsigned long long m = __ballot(k == e + 1);
                int total = __popcll(m);
                int b = 0;
                if (lane == 0 && total) b = atomicAdd(&lcnt[e], total);
                b = __shfl(b, 0, 64);
                if (k == e + 1) {
                    int p = b + __popcll(m & ((1ull << lane) - 1ull));
                    list[e * NTOK + p] = t;
                    pos_of[t] = p;
                }
            }
        }
        __syncthreads();
        if (tid == 0) {
            int s = 0, mb = 0;
            for (int e = 0; e < NEXP; ++e) {
                cnt[e] = lcnt[e];
                bases[e] = s;
                bases[8 + e] = mb;                 // 128-row panel offsets
                s += lcnt[e];
                mb += (lcnt[e] + 127) >> 7;
            }
            bases[12] = mb;
        }
        return;
    }

    int id = bid - 1;
    if (id < XBLKS) {
        size_t i = (size_t)(id * 256 + tid) * 8;
        float4 v0 = *(const float4*)(X + i);
        float4 v1 = *(const float4*)(X + i + 4);
        ushort tmp[8];
        tmp[0] = f2bf(v0.x); tmp[1] = f2bf(v0.y); tmp[2] = f2bf(v0.z); tmp[3] = f2bf(v0.w);
        tmp[4] = f2bf(v1.x); tmp[5] = f2bf(v1.y); tmp[6] = f2bf(v1.z); tmp[7] = f2bf(v1.w);
        *(uint4*)(Xb + i) = *(uint4*)tmp;
        return;
    }
    id -= XBLKS;
    if (id < W1BLKS) {
        int z = id / 576, r = id % 576;
        size_t mb = (size_t)z * DM * DF;
        transpose_tile(W1 + mb, W1t + mb, DM, DF, r % 48, r / 48, tid, tile);
        return;
    }
    id -= W1BLKS;
    {
        int z = id / 576, r = id % 576;
        size_t mb = (size_t)z * DF * DM;
        transpose_tile(W2 + mb, W2t + mb, DF, DM, r % 12, r / 12, tid, tile);
    }
}

// =====================================================================
// GEMM structure (both kernels): 256 threads = 4 waves (2M x 2N), tile
// 128x128, BK=32, per-wave 64x64 output (16 MFMA : 8 ds_read_b128 per
// K-step = m97 ratio). Double-buffered LDS (32 KiB total -> 3 blk/CU
// at ~136 unified regs = 12 waves/CU, m97 regime). k-quad XOR swizzle
// (T2, both-sides: pre-swizzled global source + swizzled ds_read
// offset, verified conflict-free in R1). XCD remap (T1).
// =====================================================================

__global__ __launch_bounds__(256) void gemm1_kernel(
    const ushort* __restrict__ Xb, const ushort* __restrict__ W1t,
    const float* __restrict__ b1, const int* __restrict__ cnt,
    const int* __restrict__ bases, const int* __restrict__ list,
    ushort* __restrict__ h1) {
    const int mb = bases[12];
    const int T = mb * 24;
    int id = blockIdx.y * 24 + blockIdx.x;
    if (id >= T) return;
    id = xcd_remap(id, T);
    const int y = id / 24;
    const int n0 = (id % 24) * 128;
    const int* mboff = bases + 8;
    const int e = (y >= mboff[1]) + (y >= mboff[2]) + (y >= mboff[3]);
    const int m0 = (y - mboff[e]) << 7;
    const int count = cnt[e];
    const int base = bases[e];
    const int NK = DM / 32;   // 24

    __shared__ __align__(16) short As[2][4096];
    __shared__ __align__(16) short Bs[2][4096];

    const int tid = threadIdx.x;
    const int wave = tid >> 6, lane = tid & 63;
    const int wm = (wave & 1) * 64, wn = (wave >> 1) * 64;
    const int lrow = lane & 15, qg = lane >> 4;

    // staging: thread stages rows rbase & rbase+64, logical quad (tid&3),
    // source pre-swizzled so linear LDS dest holds swizzled layout
    const int rbase = tid >> 2;
    const int qsrc = ((tid & 3) ^ ((rbase >> 1) & 3)) * 8;
    int r0 = min(m0 + rbase, count - 1);
    int r1 = min(m0 + rbase + 64, count - 1);
    const ushort* aP0 = Xb + (size_t)list[e * NTOK + r0] * DM + qsrc;
    const ushort* aP1 = Xb + (size_t)list[e * NTOK + r1] * DM + qsrc;
    const ushort* Wb = W1t + (size_t)e * DF * DM;
    const ushort* bP0 = Wb + (size_t)(n0 + rbase) * DM + qsrc;
    const ushort* bP1 = bP0 + (size_t)64 * DM;

    // fragment read offsets (swizzled)
    int aOff[4], bOff[4];
#pragma unroll
    for (int i = 0; i < 4; ++i) {
        int ra = wm + i * 16 + lrow;
        aOff[i] = ra * 32 + (qg ^ ((ra >> 1) & 3)) * 8;
        int rb = wn + i * 16 + lrow;
        bOff[i] = rb * 32 + (qg ^ ((rb >> 1) & 3)) * 8;
    }

    f32x4 zz = {0.f, 0.f, 0.f, 0.f};
    f32x4 acc[4][4];
#pragma unroll
    for (int i = 0; i < 4; ++i)
#pragma unroll
        for (int j = 0; j < 4; ++j) acc[i][j] = zz;

    auto STAGE = [&](int buf) {
        short* aD = &As[buf][0] + tid * 8;
        short* bD = &Bs[buf][0] + tid * 8;
        cp16(aP0, aD); cp16(aP1, aD + 2048);
        cp16(bP0, bD); cp16(bP1, bD + 2048);
        aP0 += 32; aP1 += 32; bP0 += 32; bP1 += 32;
    };

    STAGE(0);

    for (int ks = 0; ks < NK; ++ks) {
        __syncthreads();
        if (ks + 1 < NK) STAGE((ks + 1) & 1);
        const short* Ab = &As[ks & 1][0];
        const short* Bb = &Bs[ks & 1][0];
        bf16x8 av[4], bv[4];
#pragma unroll
        for (int i = 0; i < 4; ++i) av[i] = *(const bf16x8*)(Ab + aOff[i]);
#pragma unroll
        for (int j = 0; j < 4; ++j) bv[j] = *(const bf16x8*)(Bb + bOff[j]);
#pragma unroll
        for (int i = 0; i < 4; ++i)
#pragma unroll
            for (int j = 0; j < 4; ++j)
                acc[i][j] = __builtin_amdgcn_mfma_f32_16x16x32_bf16(av[i], bv[j], acc[i][j], 0, 0, 0);
    }

    float bias[4];
#pragma unroll
    for (int j = 0; j < 4; ++j)
        bias[j] = b1[e * DF + n0 + wn + j * 16 + lrow];
#pragma unroll
    for (int i = 0; i < 4; ++i) {
        int gm = m0 + wm + i * 16 + qg * 4;
#pragma unroll
        for (int j = 0; j < 4; ++j) {
            int gn = n0 + wn + j * 16 + lrow;
#pragma unroll
            for (int r = 0; r < 4; ++r) {
                int row = gm + r;
                if (row < count)
                    h1[(size_t)(base + row) * DF + gn] = f2bf(fast_gelu(acc[i][j][r] + bias[j]));
            }
        }
    }
}

__global__ __launch_bounds__(256) void gemm2_kernel(
    const ushort* __restrict__ h1, const ushort* __restrict__ W2t,
    const float* __restrict__ b2, const int* __restrict__ cnt,
    const int* __restrict__ bases, ushort* __restrict__ h2) {
    const int mb = bases[12];
    const int T = mb * 6;
    int id = blockIdx.y * 6 + blockIdx.x;
    if (id >= T) return;
    id = xcd_remap(id, T);
    const int y = id / 6;
    const int n0 = (id % 6) * 128;
    const int* mboff = bases + 8;
    const int e = (y >= mboff[1]) + (y >= mboff[2]) + (y >= mboff[3]);
    const int m0 = (y - mboff[e]) << 7;
    const int count = cnt[e];
    const int base = bases[e];
    const int NK = DF / 32;   // 96

    __shared__ __align__(16) short As[2][4096];
    __shared__ __align__(16) short Bs[2][4096];

    const int tid = threadIdx.x;
    const int wave = tid >> 6, lane = tid & 63;
    const int wm = (wave & 1) * 64, wn = (wave >> 1) * 64;
    const int lrow = lane & 15, qg = lane >> 4;

    const int rbase = tid >> 2;
    const int qsrc = ((tid & 3) ^ ((rbase >> 1) & 3)) * 8;
    int r0 = min(m0 + rbase, count - 1);
    int r1 = min(m0 + rbase + 64, count - 1);
    const ushort* aP0 = h1 + (size_t)(base + r0) * DF + qsrc;
    const ushort* aP1 = h1 + (size_t)(base + r1) * DF + qsrc;
    const ushort* Wb = W2t + (size_t)e * DM * DF;
    const ushort* bP0 = Wb + (size_t)(n0 + rbase) * DF + qsrc;
    const ushort* bP1 = bP0 + (size_t)64 * DF;

    int aOff[4], bOff[4];
#pragma unroll
    for (int i = 0; i < 4; ++i) {
        int ra = wm + i * 16 + lrow;
        aOff[i] = ra * 32 + (qg ^ ((ra >> 1) & 3)) * 8;
        int rb = wn + i * 16 + lrow;
        bOff[i] = rb * 32 + (qg ^ ((rb >> 1) & 3)) * 8;
    }

    f32x4 zz = {0.f, 0.f, 0.f, 0.f};
    f32x4 acc[4][4];
#pragma unroll
    for (int i = 0; i < 4; ++i)
#pragma unroll
        for (int j = 0; j < 4; ++j) acc[i][j] = zz;

    auto STAGE = [&](int buf) {
        short* aD = &As[buf][0] + tid * 8;
        short* bD = &Bs[buf][0] + tid * 8;
        cp16(aP0, aD); cp16(aP1, aD + 2048);
        cp16(bP0, bD); cp16(bP1, bD + 2048);
        aP0 += 32; aP1 += 32; bP0 += 32; bP1 += 32;
    };

    STAGE(0);

    for (int ks = 0; ks < NK; ++ks) {
        __syncthreads();
        if (ks + 1 < NK) STAGE((ks + 1) & 1);
        const short* Ab = &As[ks & 1][0];
        const short* Bb = &Bs[ks & 1][0];
        bf16x8 av[4], bv[4];
#pragma unroll
        for (int i = 0; i < 4; ++i) av[i] = *(const bf16x8*)(Ab + aOff[i]);
#pragma unroll
        for (int j = 0; j < 4; ++j) bv[j] = *(const bf16x8*)(Bb + bOff[j]);
#pragma unroll
        for (int i = 0; i < 4; ++i)
#pragma unroll
            for (int j = 0; j < 4; ++j)
                acc[i][j] = __builtin_amdgcn_mfma_f32_16x16x32_bf16(av[i], bv[j], acc[i][j], 0, 0, 0);
    }

    float bias[4];
#pragma unroll
    for (int j = 0; j < 4; ++j)
        bias[j] = b2[e * DM + n0 + wn + j * 16 + lrow];
#pragma unroll
    for (int i = 0; i < 4; ++i) {
        int gm = m0 + wm + i * 16 + qg * 4;
#pragma unroll
        for (int j = 0; j < 4; ++j) {
            int gn = n0 + wn + j * 16 + lrow;
#pragma unroll
            for (int r = 0; r < 4; ++r) {
                int row = gm + r;
                if (row < count)
                    h2[(size_t)(base + row) * DM + gn] = f2bf(acc[i][j][r] + bias[j]);
            }
        }
    }
}

// ---------------- finalize ----------------
__device__ __forceinline__ void block_reduce2(float& a, float& b, float* sm, int tid) {
    __syncthreads();
#pragma unroll
    for (int off = 32; off > 0; off >>= 1) {
        a += __shfl_down(a, off, 64);
        b += __shfl_down(b, off, 64);
    }
    const int wave = tid >> 6, lane = tid & 63;
    if (lane == 0) { sm[wave] = a; sm[4 + wave] = b; }
    __syncthreads();
    a = sm[0] + sm[1] + sm[2] + sm[3];
    b = sm[4] + sm[5] + sm[6] + sm[7];
}

__global__ __launch_bounds__(256) void finalize_kernel(
    const float* __restrict__ X, const int* __restrict__ type_seq,
    const int* __restrict__ pos_of, const int* __restrict__ bases,
    const ushort* __restrict__ h2,
    const float* __restrict__ ln_g, const float* __restrict__ ln_b,
    const float* __restrict__ out_g, const float* __restrict__ out_b,
    float* __restrict__ out) {
    __shared__ float sm[8];
    const int t = blockIdx.x;
    const int tid = threadIdx.x;
    const int k = type_seq[t];

    float xv[3], rv[3];
#pragma unroll
    for (int j = 0; j < 3; ++j) xv[j] = X[(size_t)t * DM + j * 256 + tid];

    if (k > 0) {
        const int e = k - 1;
        const size_t row = (size_t)(bases[e] + pos_of[t]);
        float v[3], s1 = 0.f, s2 = 0.f;
#pragma unroll
        for (int j = 0; j < 3; ++j) {
            v[j] = bf2f(h2[row * DM + j * 256 + tid]) + xv[j];
            s1 += v[j]; s2 += v[j] * v[j];
        }
        block_reduce2(s1, s2, sm, tid);
        float m = s1 * (1.f / DM);
        float inv = rsqrtf(s2 * (1.f / DM) - m * m + 1e-12f);
#pragma unroll
        for (int j = 0; j < 3; ++j) {
            int c = j * 256 + tid;
            rv[j] = (v[j] - m) * inv * ln_g[e * DM + c] + ln_b[e * DM + c];
        }
    } else {
        rv[0] = rv[1] = rv[2] = 0.f;
    }

    float w[3], s1 = 0.f, s2 = 0.f;
#pragma unroll
    for (int j = 0; j < 3; ++j) {
        w[j] = rv[j] + xv[j];
        s1 += w[j]; s2 += w[j] * w[j];
    }
    block_reduce2(s1, s2, sm, tid);
    float m = s1 * (1.f / DM);
    float inv = rsqrtf(s2 * (1.f / DM) - m * m + 1e-12f);
#pragma unroll
    for (int j = 0; j < 3; ++j) {
        int c = j * 256 + tid;
        out[(size_t)t * DM + c] = (w[j] - m) * inv * out_g[c] + out_b[c];
    }
}

// ---------------- launcher ----------------
extern "C" void kernel_launch(void* const* d_in, const int* in_sizes, int n_in,
                              void* d_out, int out_size, void* d_ws, size_t ws_size,
                              hipStream_t stream) {
    if (ws_size < (size_t)WS_END) return;

    const float* X     = (const float*)d_in[0];
    const int*   type  = (const int*)d_in[1];
    const float* W1    = (const float*)d_in[2];
    const float* b1    = (const float*)d_in[3];
    const float* W2    = (const float*)d_in[4];
    const float* b2    = (const float*)d_in[5];
    const float* ln_g  = (const float*)d_in[6];
    const float* ln_b  = (const float*)d_in[7];
    const float* out_g = (const float*)d_in[8];
    const float* out_b = (const float*)d_in[9];
    float* out = (float*)d_out;

    char* ws = (char*)d_ws;
    int* cnt    = (int*)(ws + WS_CNT);
    int* bases  = (int*)(ws + WS_BASES);
    int* pos_of = (int*)(ws + WS_POS);
    int* list   = (int*)(ws + WS_LIST);
    ushort* Xb  = (ushort*)(ws + WS_XB);
    ushort* W1t = (ushort*)(ws + WS_W1T);
    ushort* W2t = (ushort*)(ws + WS_W2T);
    ushort* h1  = (ushort*)(ws + WS_H1);
    ushort* h2  = (ushort*)(ws + WS_H2);

    prep_kernel<<<PREP_BLKS, 256, 0, stream>>>(type, X, W1, W2,
                                               cnt, bases, pos_of, list, Xb, W1t, W2t);
    gemm1_kernel<<<dim3(24, MAXP), 256, 0, stream>>>(Xb, W1t, b1, cnt, bases, list, h1);
    gemm2_kernel<<<dim3(6, MAXP), 256, 0, stream>>>(h1, W2t, b2, cnt, bases, h2);
    finalize_kernel<<<NTOK, 256, 0, stream>>>(X, type, pos_of, bases, h2, ln_g, ln_b, out_g, out_b, out);
}

// Round 4
// 419.251 us; speedup vs baseline: 1.1072x; 1.1019x over previous
//
#include <hip/hip_runtime.h>
#include <hip/hip_bf16.h>
#include <math.h>

#define NTOK   16384
#define DM     768
#define DF     3072
#define NEXP   4

// prep kernel flat-grid section sizes
#define XBLKS  6144                    // (NTOK*DM)/(256*8)
#define W1BLKS 2304                    // 4 * (DF/64) * (DM/64) = 4*48*12
#define W2BLKS 2304                    // 4 * (DM/64) * (DF/64)
#define PREP_BLKS (1 + XBLKS + W1BLKS + W2BLKS)

typedef short bf16x8 __attribute__((ext_vector_type(8)));
typedef float f32x4  __attribute__((ext_vector_type(4)));

// ---------------- workspace layout (bytes) ----------------
#define WS_CNT    0u
#define WS_BASES  256u                        // bases[4] + panel offsets (ints)
#define WS_POS    512u                        // NTOK ints            = 65536
#define WS_LIST   (512u + 65536u)             // NEXP*NTOK ints       = 262144
#define WS_XB     (WS_LIST + 262144u)         // NTOK*DM bf16         = 25165824
#define WS_W1T    (WS_XB + 25165824u)         // 4*DF*DM bf16         = 18874368
#define WS_W2T    (WS_W1T + 18874368u)        // 4*DM*DF bf16         = 18874368
#define WS_H1     (WS_W2T + 18874368u)        // NTOK*DF bf16         = 100663296
#define WS_H2     (WS_H1 + 100663296u)        // NTOK*DM bf16         = 25165824
#define WS_END    (WS_H2 + 25165824u)

// ---------------- bf16 helpers (manual, RNE) ----------------
__device__ __forceinline__ ushort f2bf(float f) {
    unsigned int v; __builtin_memcpy(&v, &f, 4);
    v = v + 0x7fffu + ((v >> 16) & 1u);
    return (ushort)(v >> 16);
}
__device__ __forceinline__ float bf2f(ushort u) {
    unsigned int v = ((unsigned int)u) << 16;
    float f; __builtin_memcpy(&f, &v, 4); return f;
}

// fast gelu: x * sigmoid(1.5957691(x + 0.044715 x^3)); exp2-based, ~1e-3 abs err
__device__ __forceinline__ float fast_gelu(float v) {
    float y = v + 0.044715f * v * v * v;
    float e = __builtin_amdgcn_exp2f(-2.3022082f * y);
    return v * __builtin_amdgcn_rcpf(1.0f + e);
}

// async global->LDS, 16B per lane. LDS dest must be uniform_base + lane*16.
typedef __attribute__((address_space(1))) const void gvoid_t;
typedef __attribute__((address_space(3))) void lvoid_t;
__device__ __forceinline__ void cp16(const void* g, void* l) {
    __builtin_amdgcn_global_load_lds((gvoid_t*)g, (lvoid_t*)l, 16, 0, 0);
}

// bijective chunked XCD remap over T active blocks (m204 formula)
__device__ __forceinline__ int xcd_remap(int id, int T) {
    const int q = T >> 3, r = T & 7;
    const int x = id & 7, j = id >> 3;
    return (x < r ? x * (q + 1) : r * (q + 1) + (x - r) * q) + j;
}

// ---------------- transpose tile helper ----------------
__device__ __forceinline__ void transpose_tile(
    const float* __restrict__ src, ushort* __restrict__ dst, int R, int C,
    int bx, int by, int tid, ushort* tile /* [64][72] */) {
    const int r0 = by * 64, c0 = bx * 64;
#pragma unroll
    for (int q = 0; q < 2; ++q) {
        int li = q * 256 + tid;
        int r = li >> 3, c = (li & 7) * 8;
        const float* s = src + (size_t)(r0 + r) * C + (c0 + c);
        float4 v0 = *(const float4*)s;
        float4 v1 = *(const float4*)(s + 4);
        ushort tmp[8];
        tmp[0] = f2bf(v0.x); tmp[1] = f2bf(v0.y); tmp[2] = f2bf(v0.z); tmp[3] = f2bf(v0.w);
        tmp[4] = f2bf(v1.x); tmp[5] = f2bf(v1.y); tmp[6] = f2bf(v1.z); tmp[7] = f2bf(v1.w);
        int sw = (((c >> 3) ^ ((r >> 3) & 7)) << 3);
        *(uint4*)&tile[r * 72 + sw] = *(uint4*)tmp;
    }
    __syncthreads();
#pragma unroll
    for (int q = 0; q < 2; ++q) {
        int li = q * 256 + tid;
        int r = li >> 3, c = (li & 7) * 8;
        ushort tmp[8];
#pragma unroll
        for (int j = 0; j < 8; ++j)
            tmp[j] = tile[(c + j) * 72 +
                          ((((r >> 3) & 7) ^ (((c + j) >> 3) & 7)) << 3) + (r & 7)];
        *(uint4*)(dst + (size_t)(c0 + r) * R + (r0 + c)) = *(uint4*)tmp;
    }
}

// ---------------- prep: routing + X cvt + W1/W2 transpose ----------------
__global__ __launch_bounds__(256) void prep_kernel(
    const int* __restrict__ type_seq, const float* __restrict__ X,
    const float* __restrict__ W1, const float* __restrict__ W2,
    int* __restrict__ cnt, int* __restrict__ bases,
    int* __restrict__ pos_of, int* __restrict__ list,
    ushort* __restrict__ Xb, ushort* __restrict__ W1t, ushort* __restrict__ W2t) {
    __shared__ ushort tile[64 * 72];
    __shared__ int lcnt[NEXP];
    const int tid = threadIdx.x;
    const int bid = blockIdx.x;

    if (bid == 0) {
        if (tid < NEXP) lcnt[tid] = 0;
        __syncthreads();
        const int lane = tid & 63;
        for (int it = 0; it < NTOK / 256; ++it) {
            int t = it * 256 + tid;
            int k = type_seq[t];
#pragma unroll
            for (int e = 0; e < NEXP; ++e) {
                unsigned long long m = __ballot(k == e + 1);
                int total = __popcll(m);
                int b = 0;
                if (lane == 0 && total) b = atomicAdd(&lcnt[e], total);
                b = __shfl(b, 0, 64);
                if (k == e + 1) {
                    int p = b + __popcll(m & ((1ull << lane) - 1ull));
                    list[e * NTOK + p] = t;
                    pos_of[t] = p;
                }
            }
        }
        __syncthreads();
        if (tid == 0) {
            int s = 0, mb = 0;
            for (int e = 0; e < NEXP; ++e) {
                cnt[e] = lcnt[e];
                bases[e] = s;
                bases[8 + e] = mb;                 // 128-row panel offsets
                s += lcnt[e];
                mb += (lcnt[e] + 127) >> 7;
            }
            bases[12] = mb;
        }
        return;
    }

    int id = bid - 1;
    if (id < XBLKS) {
        size_t i = (size_t)(id * 256 + tid) * 8;
        float4 v0 = *(const float4*)(X + i);
        float4 v1 = *(const float4*)(X + i + 4);
        ushort tmp[8];
        tmp[0] = f2bf(v0.x); tmp[1] = f2bf(v0.y); tmp[2] = f2bf(v0.z); tmp[3] = f2bf(v0.w);
        tmp[4] = f2bf(v1.x); tmp[5] = f2bf(v1.y); tmp[6] = f2bf(v1.z); tmp[7] = f2bf(v1.w);
        *(uint4*)(Xb + i) = *(uint4*)tmp;
        return;
    }
    id -= XBLKS;
    if (id < W1BLKS) {
        int z = id / 576, r = id % 576;
        size_t mb = (size_t)z * DM * DF;
        transpose_tile(W1 + mb, W1t + mb, DM, DF, r % 48, r / 48, tid, tile);
        return;
    }
    id -= W1BLKS;
    {
        int z = id / 576, r = id % 576;
        size_t mb = (size_t)z * DF * DM;
        transpose_tile(W2 + mb, W2t + mb, DF, DM, r % 12, r / 12, tid, tile);
    }
}

// =====================================================================
// GEMM structure (both kernels, = round-1 best + depth-2 pipeline):
// 512 threads = 8 waves, tile 128x128, BK=32, per-wave 64x32 output.
// TRIPLE-buffered LDS (48 KiB), prefetch depth 2, counted
// s_waitcnt vmcnt(2) + raw s_barrier (T4) -- the wait at iter k covers
// loads issued at iter k-2 (two K-steps + 8-wave stagger of cover);
// vmcnt(0) only at the last iteration. sched_barrier(0) fences pin
// ordering (rule #18). k-quad XOR swizzle as round 1 (conflict-free).
// =====================================================================

__global__ __launch_bounds__(512, 4) void gemm1_kernel(
    const ushort* __restrict__ Xb, const ushort* __restrict__ W1t,
    const float* __restrict__ b1, const int* __restrict__ cnt,
    const int* __restrict__ bases, const int* __restrict__ list,
    ushort* __restrict__ h1) {
    const int mb = bases[12];
    const int T = mb * 24;
    int id = blockIdx.y * 24 + blockIdx.x;
    if (id >= T) return;
    id = xcd_remap(id, T);
    const int y = id / 24;
    const int n0 = (id % 24) * 128;
    const int* mboff = bases + 8;
    const int e = (y >= mboff[1]) + (y >= mboff[2]) + (y >= mboff[3]);
    const int m0 = (y - mboff[e]) << 7;
    const int count = cnt[e];
    const int NK = DM / 32;   // 24

    __shared__ __align__(16) short As[3][4096];
    __shared__ __align__(16) short Bs[3][4096];

    const int tid = threadIdx.x;
    const int wave = tid >> 6, lane = tid & 63;
    const int wm = (wave & 1) * 64, wn = (wave >> 1) * 32;
    const int lrow = lane & 15;
    const int qg = lane >> 4;

    int r0 = min(m0 + (tid >> 2), count - 1);
    int t0 = list[e * NTOK + r0];
    const int qsrc = ((tid & 3) ^ ((tid >> 3) & 3)) * 8;   // source k-quad pre-swizzle
    const ushort* a0 = Xb + (size_t)t0 * DM + qsrc;
    const ushort* Wb = W1t + (size_t)e * DF * DM;
    const ushort* bp0 = Wb + (size_t)(n0 + (tid >> 2)) * DM + qsrc;

    int aOff[4], bOff[2];
#pragma unroll
    for (int i = 0; i < 4; ++i) {
        int ra = wm + i * 16 + lrow;
        aOff[i] = ra * 32 + (qg ^ ((ra >> 1) & 3)) * 8;
    }
#pragma unroll
    for (int j = 0; j < 2; ++j) {
        int rb = wn + j * 16 + lrow;
        bOff[j] = rb * 32 + (qg ^ ((rb >> 1) & 3)) * 8;
    }

    f32x4 z = {0.f, 0.f, 0.f, 0.f};
    f32x4 acc[4][2];
#pragma unroll
    for (int i = 0; i < 4; ++i)
#pragma unroll
        for (int j = 0; j < 2; ++j) acc[i][j] = z;

    auto STAGE = [&](int wb) {
        cp16(a0, &As[0][0] + wb * 4096 + tid * 8);
        cp16(bp0, &Bs[0][0] + wb * 4096 + tid * 8);
        a0 += 32; bp0 += 32;
    };

    STAGE(0); STAGE(1);                         // depth-2 prologue, 4 cp16 in flight
    int rb = 0;
    for (int ks = 0; ks < NK; ++ks) {
        __builtin_amdgcn_sched_barrier(0);
        if (ks + 1 < NK) { asm volatile("s_waitcnt vmcnt(2)" ::: "memory"); }
        else             { asm volatile("s_waitcnt vmcnt(0)" ::: "memory"); }
        __builtin_amdgcn_s_barrier();
        __builtin_amdgcn_sched_barrier(0);
        if (ks + 2 < NK) {
            int wb = rb - 1; if (wb < 0) wb += 3;   // (ks+2)%3
            STAGE(wb);
        }
        const short* Ab = &As[0][0] + rb * 4096;
        const short* Bb = &Bs[0][0] + rb * 4096;
        bf16x8 av[4], bv[2];
#pragma unroll
        for (int i = 0; i < 4; ++i) av[i] = *(const bf16x8*)(Ab + aOff[i]);
#pragma unroll
        for (int j = 0; j < 2; ++j) bv[j] = *(const bf16x8*)(Bb + bOff[j]);
#pragma unroll
        for (int i = 0; i < 4; ++i)
#pragma unroll
            for (int j = 0; j < 2; ++j)
                acc[i][j] = __builtin_amdgcn_mfma_f32_16x16x32_bf16(av[i], bv[j], acc[i][j], 0, 0, 0);
        rb = (rb + 1 == 3) ? 0 : rb + 1;
    }

    const int base = bases[e];
    float bias[2];
#pragma unroll
    for (int nt = 0; nt < 2; ++nt)
        bias[nt] = b1[e * DF + n0 + wn + nt * 16 + lrow];
#pragma unroll
    for (int mt = 0; mt < 4; ++mt) {
        int gm = m0 + wm + mt * 16 + (lane >> 4) * 4;
#pragma unroll
        for (int nt = 0; nt < 2; ++nt) {
            int gn = n0 + wn + nt * 16 + lrow;
#pragma unroll
            for (int r = 0; r < 4; ++r) {
                int i = gm + r;
                if (i < count) {
                    float v = acc[mt][nt][r] + bias[nt];
                    h1[(size_t)(base + i) * DF + gn] = f2bf(fast_gelu(v));
                }
            }
        }
    }
}

__global__ __launch_bounds__(512, 4) void gemm2_kernel(
    const ushort* __restrict__ h1, const ushort* __restrict__ W2t,
    const float* __restrict__ b2, const int* __restrict__ cnt,
    const int* __restrict__ bases, ushort* __restrict__ h2) {
    const int mb = bases[12];
    const int T = mb * 6;
    int id = blockIdx.y * 6 + blockIdx.x;
    if (id >= T) return;
    id = xcd_remap(id, T);
    const int y = id / 6;
    const int n0 = (id % 6) * 128;
    const int* mboff = bases + 8;
    const int e = (y >= mboff[1]) + (y >= mboff[2]) + (y >= mboff[3]);
    const int m0 = (y - mboff[e]) << 7;
    const int count = cnt[e];
    const int base = bases[e];
    const int NK = DF / 32;   // 96

    __shared__ __align__(16) short As[3][4096];
    __shared__ __align__(16) short Bs[3][4096];

    const int tid = threadIdx.x;
    const int wave = tid >> 6, lane = tid & 63;
    const int wm = (wave & 1) * 64, wn = (wave >> 1) * 32;
    const int lrow = lane & 15;
    const int qg = lane >> 4;

    int r0 = min(m0 + (tid >> 2), count - 1);
    const int qsrc = ((tid & 3) ^ ((tid >> 3) & 3)) * 8;
    const ushort* a0 = h1 + (size_t)(base + r0) * DF + qsrc;
    const ushort* Wb = W2t + (size_t)e * DM * DF;
    const ushort* bp0 = Wb + (size_t)(n0 + (tid >> 2)) * DF + qsrc;

    int aOff[4], bOff[2];
#pragma unroll
    for (int i = 0; i < 4; ++i) {
        int ra = wm + i * 16 + lrow;
        aOff[i] = ra * 32 + (qg ^ ((ra >> 1) & 3)) * 8;
    }
#pragma unroll
    for (int j = 0; j < 2; ++j) {
        int rb = wn + j * 16 + lrow;
        bOff[j] = rb * 32 + (qg ^ ((rb >> 1) & 3)) * 8;
    }

    f32x4 z = {0.f, 0.f, 0.f, 0.f};
    f32x4 acc[4][2];
#pragma unroll
    for (int i = 0; i < 4; ++i)
#pragma unroll
        for (int j = 0; j < 2; ++j) acc[i][j] = z;

    auto STAGE = [&](int wb) {
        cp16(a0, &As[0][0] + wb * 4096 + tid * 8);
        cp16(bp0, &Bs[0][0] + wb * 4096 + tid * 8);
        a0 += 32; bp0 += 32;
    };

    STAGE(0); STAGE(1);
    int rb = 0;
    for (int ks = 0; ks < NK; ++ks) {
        __builtin_amdgcn_sched_barrier(0);
        if (ks + 1 < NK) { asm volatile("s_waitcnt vmcnt(2)" ::: "memory"); }
        else             { asm volatile("s_waitcnt vmcnt(0)" ::: "memory"); }
        __builtin_amdgcn_s_barrier();
        __builtin_amdgcn_sched_barrier(0);
        if (ks + 2 < NK) {
            int wb = rb - 1; if (wb < 0) wb += 3;
            STAGE(wb);
        }
        const short* Ab = &As[0][0] + rb * 4096;
        const short* Bb = &Bs[0][0] + rb * 4096;
        bf16x8 av[4], bv[2];
#pragma unroll
        for (int i = 0; i < 4; ++i) av[i] = *(const bf16x8*)(Ab + aOff[i]);
#pragma unroll
        for (int j = 0; j < 2; ++j) bv[j] = *(const bf16x8*)(Bb + bOff[j]);
#pragma unroll
        for (int i = 0; i < 4; ++i)
#pragma unroll
            for (int j = 0; j < 2; ++j)
                acc[i][j] = __builtin_amdgcn_mfma_f32_16x16x32_bf16(av[i], bv[j], acc[i][j], 0, 0, 0);
        rb = (rb + 1 == 3) ? 0 : rb + 1;
    }

    float bias[2];
#pragma unroll
    for (int nt = 0; nt < 2; ++nt)
        bias[nt] = b2[e * DM + n0 + wn + nt * 16 + lrow];
#pragma unroll
    for (int mt = 0; mt < 4; ++mt) {
        int gm = m0 + wm + mt * 16 + (lane >> 4) * 4;
#pragma unroll
        for (int nt = 0; nt < 2; ++nt) {
            int gn = n0 + wn + nt * 16 + lrow;
#pragma unroll
            for (int r = 0; r < 4; ++r) {
                int i = gm + r;
                if (i < count)
                    h2[(size_t)(base + i) * DM + gn] = f2bf(acc[mt][nt][r] + bias[nt]);
            }
        }
    }
}

// ---------------- finalize ----------------
__device__ __forceinline__ void block_reduce2(float& a, float& b, float* sm, int tid) {
    __syncthreads();
#pragma unroll
    for (int off = 32; off > 0; off >>= 1) {
        a += __shfl_down(a, off, 64);
        b += __shfl_down(b, off, 64);
    }
    const int wave = tid >> 6, lane = tid & 63;
    if (lane == 0) { sm[wave] = a; sm[4 + wave] = b; }
    __syncthreads();
    a = sm[0] + sm[1] + sm[2] + sm[3];
    b = sm[4] + sm[5] + sm[6] + sm[7];
}

__global__ __launch_bounds__(256) void finalize_kernel(
    const float* __restrict__ X, const int* __restrict__ type_seq,
    const int* __restrict__ pos_of, const int* __restrict__ bases,
    const ushort* __restrict__ h2,
    const float* __restrict__ ln_g, const float* __restrict__ ln_b,
    const float* __restrict__ out_g, const float* __restrict__ out_b,
    float* __restrict__ out) {
    __shared__ float sm[8];
    const int t = blockIdx.x;
    const int tid = threadIdx.x;
    const int k = type_seq[t];

    float xv[3], rv[3];
#pragma unroll
    for (int j = 0; j < 3; ++j) xv[j] = X[(size_t)t * DM + j * 256 + tid];

    if (k > 0) {
        const int e = k - 1;
        const size_t row = (size_t)(bases[e] + pos_of[t]);
        float v[3], s1 = 0.f, s2 = 0.f;
#pragma unroll
        for (int j = 0; j < 3; ++j) {
            v[j] = bf2f(h2[row * DM + j * 256 + tid]) + xv[j];
            s1 += v[j]; s2 += v[j] * v[j];
        }
        block_reduce2(s1, s2, sm, tid);
        float m = s1 * (1.f / DM);
        float inv = rsqrtf(s2 * (1.f / DM) - m * m + 1e-12f);
#pragma unroll
        for (int j = 0; j < 3; ++j) {
            int c = j * 256 + tid;
            rv[j] = (v[j] - m) * inv * ln_g[e * DM + c] + ln_b[e * DM + c];
        }
    } else {
        rv[0] = rv[1] = rv[2] = 0.f;
    }

    float w[3], s1 = 0.f, s2 = 0.f;
#pragma unroll
    for (int j = 0; j < 3; ++j) {
        w[j] = rv[j] + xv[j];
        s1 += w[j]; s2 += w[j] * w[j];
    }
    block_reduce2(s1, s2, sm, tid);
    float m = s1 * (1.f / DM);
    float inv = rsqrtf(s2 * (1.f / DM) - m * m + 1e-12f);
#pragma unroll
    for (int j = 0; j < 3; ++j) {
        int c = j * 256 + tid;
        out[(size_t)t * DM + c] = (w[j] - m) * inv * out_g[c] + out_b[c];
    }
}

// ---------------- launcher ----------------
extern "C" void kernel_launch(void* const* d_in, const int* in_sizes, int n_in,
                              void* d_out, int out_size, void* d_ws, size_t ws_size,
                              hipStream_t stream) {
    if (ws_size < (size_t)WS_END) return;

    const float* X     = (const float*)d_in[0];
    const int*   type  = (const int*)d_in[1];
    const float* W1    = (const float*)d_in[2];
    const float* b1    = (const float*)d_in[3];
    const float* W2    = (const float*)d_in[4];
    const float* b2    = (const float*)d_in[5];
    const float* ln_g  = (const float*)d_in[6];
    const float* ln_b  = (const float*)d_in[7];
    const float* out_g = (const float*)d_in[8];
    const float* out_b = (const float*)d_in[9];
    float* out = (float*)d_out;

    char* ws = (char*)d_ws;
    int* cnt    = (int*)(ws + WS_CNT);
    int* bases  = (int*)(ws + WS_BASES);
    int* pos_of = (int*)(ws + WS_POS);
    int* list   = (int*)(ws + WS_LIST);
    ushort* Xb  = (ushort*)(ws + WS_XB);
    ushort* W1t = (ushort*)(ws + WS_W1T);
    ushort* W2t = (ushort*)(ws + WS_W2T);
    ushort* h1  = (ushort*)(ws + WS_H1);
    ushort* h2  = (ushort*)(ws + WS_H2);

    prep_kernel<<<PREP_BLKS, 256, 0, stream>>>(type, X, W1, W2,
                                               cnt, bases, pos_of, list, Xb, W1t, W2t);
    gemm1_kernel<<<dim3(24, 132), 512, 0, stream>>>(Xb, W1t, b1, cnt, bases, list, h1);
    gemm2_kernel<<<dim3(6, 132), 512, 0, stream>>>(h1, W2t, b2, cnt, bases, h2);
    finalize_kernel<<<NTOK, 256, 0, stream>>>(X, type, pos_of, bases, h2, ln_g, ln_b, out_g, out_b, out);
}

// Round 5
// 385.468 us; speedup vs baseline: 1.2042x; 1.0876x over previous
//
#include <hip/hip_runtime.h>
#include <hip/hip_bf16.h>
#include <math.h>

#define NTOK   16384
#define DM     768
#define DF     3072
#define NEXP   4

// prep kernel fat-grid sections (fewer, fatter blocks: dispatch-rate fix)
#define RBLKS  64                      // routing: NTOK/256 tokens per block
#define XBLKS  768                     // X cvt: 8 units of 2048 elems each
#define WBLKS  288                     // per-W transpose: 8 tiles of 64x64 each
#define PREP_BLKS (RBLKS + XBLKS + 2 * WBLKS)   // 1408

typedef short bf16x8 __attribute__((ext_vector_type(8)));
typedef float f32x4  __attribute__((ext_vector_type(4)));

// ---------------- workspace layout (bytes) ----------------
#define WS_CNT    0u
#define WS_BASES  256u                        // bases[4] + panel offsets (ints)
#define WS_POS    512u                        // NTOK ints            = 65536
#define WS_LIST   (512u + 65536u)             // NEXP*NTOK ints       = 262144
#define WS_XB     (WS_LIST + 262144u)         // NTOK*DM bf16         = 25165824
#define WS_W1T    (WS_XB + 25165824u)         // 4*DF*DM bf16         = 18874368
#define WS_W2T    (WS_W1T + 18874368u)        // 4*DM*DF bf16         = 18874368
#define WS_H1     (WS_W2T + 18874368u)        // NTOK*DF bf16         = 100663296
#define WS_H2     (WS_H1 + 100663296u)        // NTOK*DM bf16         = 25165824
#define WS_END    (WS_H2 + 25165824u)

// ---------------- bf16 helpers (manual, RNE) ----------------
__device__ __forceinline__ ushort f2bf(float f) {
    unsigned int v; __builtin_memcpy(&v, &f, 4);
    v = v + 0x7fffu + ((v >> 16) & 1u);
    return (ushort)(v >> 16);
}
__device__ __forceinline__ float bf2f(ushort u) {
    unsigned int v = ((unsigned int)u) << 16;
    float f; __builtin_memcpy(&f, &v, 4); return f;
}

// fast gelu: x * sigmoid(1.5957691(x + 0.044715 x^3)); exp2-based, ~1e-3 abs err
__device__ __forceinline__ float fast_gelu(float v) {
    float y = v + 0.044715f * v * v * v;
    float e = __builtin_amdgcn_exp2f(-2.3022082f * y);
    return v * __builtin_amdgcn_rcpf(1.0f + e);
}

// async global->LDS, 16B per lane. LDS dest must be uniform_base + lane*16.
typedef __attribute__((address_space(1))) const void gvoid_t;
typedef __attribute__((address_space(3))) void lvoid_t;
__device__ __forceinline__ void cp16(const void* g, void* l) {
    __builtin_amdgcn_global_load_lds((gvoid_t*)g, (lvoid_t*)l, 16, 0, 0);
}

// bijective chunked XCD remap over T active blocks (m204 formula)
__device__ __forceinline__ int xcd_remap(int id, int T) {
    const int q = T >> 3, r = T & 7;
    const int x = id & 7, j = id >> 3;
    return (x < r ? x * (q + 1) : r * (q + 1) + (x - r) * q) + j;
}

// ---------------- transpose tile helper ----------------
__device__ __forceinline__ void transpose_tile(
    const float* __restrict__ src, ushort* __restrict__ dst, int R, int C,
    int bx, int by, int tid, ushort* tile /* [64][72] */) {
    const int r0 = by * 64, c0 = bx * 64;
#pragma unroll
    for (int q = 0; q < 2; ++q) {
        int li = q * 256 + tid;
        int r = li >> 3, c = (li & 7) * 8;
        const float* s = src + (size_t)(r0 + r) * C + (c0 + c);
        float4 v0 = *(const float4*)s;
        float4 v1 = *(const float4*)(s + 4);
        ushort tmp[8];
        tmp[0] = f2bf(v0.x); tmp[1] = f2bf(v0.y); tmp[2] = f2bf(v0.z); tmp[3] = f2bf(v0.w);
        tmp[4] = f2bf(v1.x); tmp[5] = f2bf(v1.y); tmp[6] = f2bf(v1.z); tmp[7] = f2bf(v1.w);
        int sw = (((c >> 3) ^ ((r >> 3) & 7)) << 3);
        *(uint4*)&tile[r * 72 + sw] = *(uint4*)tmp;
    }
    __syncthreads();
#pragma unroll
    for (int q = 0; q < 2; ++q) {
        int li = q * 256 + tid;
        int r = li >> 3, c = (li & 7) * 8;
        ushort tmp[8];
#pragma unroll
        for (int j = 0; j < 8; ++j)
            tmp[j] = tile[(c + j) * 72 +
                          ((((r >> 3) & 7) ^ (((c + j) >> 3) & 7)) << 3) + (r & 7)];
        *(uint4*)(dst + (size_t)(c0 + r) * R + (r0 + c)) = *(uint4*)tmp;
    }
}

// ---------------- prep: parallel routing + X cvt + W1/W2 transpose ----------------
// Routing: 64 blocks; per-block ballot prefix via LDS atomics, then ONE global
// atomicAdd(cnt[e]) per block per expert to claim a segment offset. Expert-list
// order is nondeterministic across blocks; per-token results are order-invariant.
// cnt[] must be zeroed before launch (hipMemsetAsync in launcher).
__global__ __launch_bounds__(256) void prep_kernel(
    const int* __restrict__ type_seq, const float* __restrict__ X,
    const float* __restrict__ W1, const float* __restrict__ W2,
    int* __restrict__ cnt,
    int* __restrict__ pos_of, int* __restrict__ list,
    ushort* __restrict__ Xb, ushort* __restrict__ W1t, ushort* __restrict__ W2t) {
    __shared__ ushort tile[64 * 72];
    __shared__ int lcnt[NEXP];
    __shared__ int lbase[NEXP];
    const int tid = threadIdx.x;
    const int bid = blockIdx.x;

    if (bid < RBLKS) {
        // ---- parallel routing: this block owns tokens [bid*256, bid*256+256) ----
        if (tid < NEXP) lcnt[tid] = 0;
        __syncthreads();
        const int lane = tid & 63;
        const int t = bid * 256 + tid;
        const int k = type_seq[t];
        int my_e = -1, my_p = 0;
#pragma unroll
        for (int e = 0; e < NEXP; ++e) {
            unsigned long long m = __ballot(k == e + 1);
            int total = __popcll(m);
            int b = 0;
            if (lane == 0 && total) b = atomicAdd(&lcnt[e], total);
            b = __shfl(b, 0, 64);
            if (k == e + 1) {
                my_e = e;
                my_p = b + __popcll(m & ((1ull << lane) - 1ull));
            }
        }
        __syncthreads();
        if (tid < NEXP && lcnt[tid] > 0)
            lbase[tid] = atomicAdd(&cnt[tid], lcnt[tid]);   // global, device-scope
        __syncthreads();
        if (my_e >= 0) {
            int gp = lbase[my_e] + my_p;
            list[my_e * NTOK + gp] = t;
            pos_of[t] = gp;
        }
        return;
    }

    int id = bid - RBLKS;
    if (id < XBLKS) {
        // ---- X fp32 -> bf16, 8 batched units per block (256B/thread in flight) ----
        size_t ibase = ((size_t)id * 8 * 256 + tid) * 8;
        float4 va[8], vb[8];
#pragma unroll
        for (int k = 0; k < 8; ++k) {
            va[k] = *(const float4*)(X + ibase + (size_t)k * 2048);
            vb[k] = *(const float4*)(X + ibase + (size_t)k * 2048 + 4);
        }
#pragma unroll
        for (int k = 0; k < 8; ++k) {
            ushort tmp[8];
            tmp[0] = f2bf(va[k].x); tmp[1] = f2bf(va[k].y);
            tmp[2] = f2bf(va[k].z); tmp[3] = f2bf(va[k].w);
            tmp[4] = f2bf(vb[k].x); tmp[5] = f2bf(vb[k].y);
            tmp[6] = f2bf(vb[k].z); tmp[7] = f2bf(vb[k].w);
            *(uint4*)(Xb + ibase + (size_t)k * 2048) = *(uint4*)tmp;
        }
        return;
    }
    id -= XBLKS;
    if (id < WBLKS) {
        // ---- W1 [z][768][3072] -> W1t [z][3072][768], 8 tiles per block ----
#pragma unroll 1
        for (int k = 0; k < 8; ++k) {
            int tt = id * 8 + k;
            int z = tt / 576, rr = tt % 576;
            size_t mb = (size_t)z * DM * DF;
            transpose_tile(W1 + mb, W1t + mb, DM, DF, rr % 48, rr / 48, tid, tile);
            __syncthreads();   // protect tile reuse across iterations
        }
        return;
    }
    id -= WBLKS;
    {
        // ---- W2 [z][3072][768] -> W2t [z][768][3072], 8 tiles per block ----
#pragma unroll 1
        for (int k = 0; k < 8; ++k) {
            int tt = id * 8 + k;
            int z = tt / 576, rr = tt % 576;
            size_t mb = (size_t)z * DF * DM;
            transpose_tile(W2 + mb, W2t + mb, DF, DM, rr % 12, rr / 12, tid, tile);
            __syncthreads();
        }
    }
}

// ---------------- scan: bases + 128-row panel offsets from cnt ----------------
__global__ __launch_bounds__(64) void scan_kernel(
    const int* __restrict__ cnt, int* __restrict__ bases) {
    if (threadIdx.x == 0) {
        int s = 0, mb = 0;
        for (int e = 0; e < NEXP; ++e) {
            bases[e] = s;
            bases[8 + e] = mb;
            s += cnt[e];
            mb += (cnt[e] + 127) >> 7;
        }
        bases[12] = mb;
    }
}

// =====================================================================
// GEMM structure (both kernels, verified round-4 best):
// 512 threads = 8 waves, tile 128x128, BK=32, per-wave 64x32 output.
// TRIPLE-buffered LDS (48 KiB), prefetch depth 2, counted
// s_waitcnt vmcnt(2) + raw s_barrier (T4); vmcnt(0) only at the last
// iteration. sched_barrier(0) fences pin ordering (rule #18).
// k-quad XOR swizzle (T2, both-sides, conflict-free). XCD remap (T1).
// =====================================================================

__global__ __launch_bounds__(512, 4) void gemm1_kernel(
    const ushort* __restrict__ Xb, const ushort* __restrict__ W1t,
    const float* __restrict__ b1, const int* __restrict__ cnt,
    const int* __restrict__ bases, const int* __restrict__ list,
    ushort* __restrict__ h1) {
    const int mb = bases[12];
    const int T = mb * 24;
    int id = blockIdx.y * 24 + blockIdx.x;
    if (id >= T) return;
    id = xcd_remap(id, T);
    const int y = id / 24;
    const int n0 = (id % 24) * 128;
    const int* mboff = bases + 8;
    const int e = (y >= mboff[1]) + (y >= mboff[2]) + (y >= mboff[3]);
    const int m0 = (y - mboff[e]) << 7;
    const int count = cnt[e];
    const int NK = DM / 32;   // 24

    __shared__ __align__(16) short As[3][4096];
    __shared__ __align__(16) short Bs[3][4096];

    const int tid = threadIdx.x;
    const int wave = tid >> 6, lane = tid & 63;
    const int wm = (wave & 1) * 64, wn = (wave >> 1) * 32;
    const int lrow = lane & 15;
    const int qg = lane >> 4;

    int r0 = min(m0 + (tid >> 2), count - 1);
    int t0 = list[e * NTOK + r0];
    const int qsrc = ((tid & 3) ^ ((tid >> 3) & 3)) * 8;   // source k-quad pre-swizzle
    const ushort* a0 = Xb + (size_t)t0 * DM + qsrc;
    const ushort* Wb = W1t + (size_t)e * DF * DM;
    const ushort* bp0 = Wb + (size_t)(n0 + (tid >> 2)) * DM + qsrc;

    int aOff[4], bOff[2];
#pragma unroll
    for (int i = 0; i < 4; ++i) {
        int ra = wm + i * 16 + lrow;
        aOff[i] = ra * 32 + (qg ^ ((ra >> 1) & 3)) * 8;
    }
#pragma unroll
    for (int j = 0; j < 2; ++j) {
        int rb = wn + j * 16 + lrow;
        bOff[j] = rb * 32 + (qg ^ ((rb >> 1) & 3)) * 8;
    }

    f32x4 z = {0.f, 0.f, 0.f, 0.f};
    f32x4 acc[4][2];
#pragma unroll
    for (int i = 0; i < 4; ++i)
#pragma unroll
        for (int j = 0; j < 2; ++j) acc[i][j] = z;

    auto STAGE = [&](int wb) {
        cp16(a0, &As[0][0] + wb * 4096 + tid * 8);
        cp16(bp0, &Bs[0][0] + wb * 4096 + tid * 8);
        a0 += 32; bp0 += 32;
    };

    STAGE(0); STAGE(1);                         // depth-2 prologue, 4 cp16 in flight
    int rb = 0;
    for (int ks = 0; ks < NK; ++ks) {
        __builtin_amdgcn_sched_barrier(0);
        if (ks + 1 < NK) { asm volatile("s_waitcnt vmcnt(2)" ::: "memory"); }
        else             { asm volatile("s_waitcnt vmcnt(0)" ::: "memory"); }
        __builtin_amdgcn_s_barrier();
        __builtin_amdgcn_sched_barrier(0);
        if (ks + 2 < NK) {
            int wb = rb - 1; if (wb < 0) wb += 3;   // (ks+2)%3
            STAGE(wb);
        }
        const short* Ab = &As[0][0] + rb * 4096;
        const short* Bb = &Bs[0][0] + rb * 4096;
        bf16x8 av[4], bv[2];
#pragma unroll
        for (int i = 0; i < 4; ++i) av[i] = *(const bf16x8*)(Ab + aOff[i]);
#pragma unroll
        for (int j = 0; j < 2; ++j) bv[j] = *(const bf16x8*)(Bb + bOff[j]);
#pragma unroll
        for (int i = 0; i < 4; ++i)
#pragma unroll
            for (int j = 0; j < 2; ++j)
                acc[i][j] = __builtin_amdgcn_mfma_f32_16x16x32_bf16(av[i], bv[j], acc[i][j], 0, 0, 0);
        rb = (rb + 1 == 3) ? 0 : rb + 1;
    }

    const int base = bases[e];
    float bias[2];
#pragma unroll
    for (int nt = 0; nt < 2; ++nt)
        bias[nt] = b1[e * DF + n0 + wn + nt * 16 + lrow];
#pragma unroll
    for (int mt = 0; mt < 4; ++mt) {
        int gm = m0 + wm + mt * 16 + (lane >> 4) * 4;
#pragma unroll
        for (int nt = 0; nt < 2; ++nt) {
            int gn = n0 + wn + nt * 16 + lrow;
#pragma unroll
            for (int r = 0; r < 4; ++r) {
                int i = gm + r;
                if (i < count) {
                    float v = acc[mt][nt][r] + bias[nt];
                    h1[(size_t)(base + i) * DF + gn] = f2bf(fast_gelu(v));
                }
            }
        }
    }
}

__global__ __launch_bounds__(512, 4) void gemm2_kernel(
    const ushort* __restrict__ h1, const ushort* __restrict__ W2t,
    const float* __restrict__ b2, const int* __restrict__ cnt,
    const int* __restrict__ bases, ushort* __restrict__ h2) {
    const int mb = bases[12];
    const int T = mb * 6;
    int id = blockIdx.y * 6 + blockIdx.x;
    if (id >= T) return;
    id = xcd_remap(id, T);
    const int y = id / 6;
    const int n0 = (id % 6) * 128;
    const int* mboff = bases + 8;
    const int e = (y >= mboff[1]) + (y >= mboff[2]) + (y >= mboff[3]);
    const int m0 = (y - mboff[e]) << 7;
    const int count = cnt[e];
    const int base = bases[e];
    const int NK = DF / 32;   // 96

    __shared__ __align__(16) short As[3][4096];
    __shared__ __align__(16) short Bs[3][4096];

    const int tid = threadIdx.x;
    const int wave = tid >> 6, lane = tid & 63;
    const int wm = (wave & 1) * 64, wn = (wave >> 1) * 32;
    const int lrow = lane & 15;
    const int qg = lane >> 4;

    int r0 = min(m0 + (tid >> 2), count - 1);
    const int qsrc = ((tid & 3) ^ ((tid >> 3) & 3)) * 8;
    const ushort* a0 = h1 + (size_t)(base + r0) * DF + qsrc;
    const ushort* Wb = W2t + (size_t)e * DM * DF;
    const ushort* bp0 = Wb + (size_t)(n0 + (tid >> 2)) * DF + qsrc;

    int aOff[4], bOff[2];
#pragma unroll
    for (int i = 0; i < 4; ++i) {
        int ra = wm + i * 16 + lrow;
        aOff[i] = ra * 32 + (qg ^ ((ra >> 1) & 3)) * 8;
    }
#pragma unroll
    for (int j = 0; j < 2; ++j) {
        int rb = wn + j * 16 + lrow;
        bOff[j] = rb * 32 + (qg ^ ((rb >> 1) & 3)) * 8;
    }

    f32x4 z = {0.f, 0.f, 0.f, 0.f};
    f32x4 acc[4][2];
#pragma unroll
    for (int i = 0; i < 4; ++i)
#pragma unroll
        for (int j = 0; j < 2; ++j) acc[i][j] = z;

    auto STAGE = [&](int wb) {
        cp16(a0, &As[0][0] + wb * 4096 + tid * 8);
        cp16(bp0, &Bs[0][0] + wb * 4096 + tid * 8);
        a0 += 32; bp0 += 32;
    };

    STAGE(0); STAGE(1);
    int rb = 0;
    for (int ks = 0; ks < NK; ++ks) {
        __builtin_amdgcn_sched_barrier(0);
        if (ks + 1 < NK) { asm volatile("s_waitcnt vmcnt(2)" ::: "memory"); }
        else             { asm volatile("s_waitcnt vmcnt(0)" ::: "memory"); }
        __builtin_amdgcn_s_barrier();
        __builtin_amdgcn_sched_barrier(0);
        if (ks + 2 < NK) {
            int wb = rb - 1; if (wb < 0) wb += 3;
            STAGE(wb);
        }
        const short* Ab = &As[0][0] + rb * 4096;
        const short* Bb = &Bs[0][0] + rb * 4096;
        bf16x8 av[4], bv[2];
#pragma unroll
        for (int i = 0; i < 4; ++i) av[i] = *(const bf16x8*)(Ab + aOff[i]);
#pragma unroll
        for (int j = 0; j < 2; ++j) bv[j] = *(const bf16x8*)(Bb + bOff[j]);
#pragma unroll
        for (int i = 0; i < 4; ++i)
#pragma unroll
            for (int j = 0; j < 2; ++j)
                acc[i][j] = __builtin_amdgcn_mfma_f32_16x16x32_bf16(av[i], bv[j], acc[i][j], 0, 0, 0);
        rb = (rb + 1 == 3) ? 0 : rb + 1;
    }

    float bias[2];
#pragma unroll
    for (int nt = 0; nt < 2; ++nt)
        bias[nt] = b2[e * DM + n0 + wn + nt * 16 + lrow];
#pragma unroll
    for (int mt = 0; mt < 4; ++mt) {
        int gm = m0 + wm + mt * 16 + (lane >> 4) * 4;
#pragma unroll
        for (int nt = 0; nt < 2; ++nt) {
            int gn = n0 + wn + nt * 16 + lrow;
#pragma unroll
            for (int r = 0; r < 4; ++r) {
                int i = gm + r;
                if (i < count)
                    h2[(size_t)(base + i) * DM + gn] = f2bf(acc[mt][nt][r] + bias[nt]);
            }
        }
    }
}

// ---------------- finalize ----------------
__device__ __forceinline__ void block_reduce2(float& a, float& b, float* sm, int tid) {
    __syncthreads();
#pragma unroll
    for (int off = 32; off > 0; off >>= 1) {
        a += __shfl_down(a, off, 64);
        b += __shfl_down(b, off, 64);
    }
    const int wave = tid >> 6, lane = tid & 63;
    if (lane == 0) { sm[wave] = a; sm[4 + wave] = b; }
    __syncthreads();
    a = sm[0] + sm[1] + sm[2] + sm[3];
    b = sm[4] + sm[5] + sm[6] + sm[7];
}

__global__ __launch_bounds__(256) void finalize_kernel(
    const float* __restrict__ X, const int* __restrict__ type_seq,
    const int* __restrict__ pos_of, const int* __restrict__ bases,
    const ushort* __restrict__ h2,
    const float* __restrict__ ln_g, const float* __restrict__ ln_b,
    const float* __restrict__ out_g, const float* __restrict__ out_b,
    float* __restrict__ out) {
    __shared__ float sm[8];
    const int t = blockIdx.x;
    const int tid = threadIdx.x;
    const int k = type_seq[t];

    float xv[3], rv[3];
#pragma unroll
    for (int j = 0; j < 3; ++j) xv[j] = X[(size_t)t * DM + j * 256 + tid];

    if (k > 0) {
        const int e = k - 1;
        const size_t row = (size_t)(bases[e] + pos_of[t]);
        float v[3], s1 = 0.f, s2 = 0.f;
#pragma unroll
        for (int j = 0; j < 3; ++j) {
            v[j] = bf2f(h2[row * DM + j * 256 + tid]) + xv[j];
            s1 += v[j]; s2 += v[j] * v[j];
        }
        block_reduce2(s1, s2, sm, tid);
        float m = s1 * (1.f / DM);
        float inv = rsqrtf(s2 * (1.f / DM) - m * m + 1e-12f);
#pragma unroll
        for (int j = 0; j < 3; ++j) {
            int c = j * 256 + tid;
            rv[j] = (v[j] - m) * inv * ln_g[e * DM + c] + ln_b[e * DM + c];
        }
    } else {
        rv[0] = rv[1] = rv[2] = 0.f;
    }

    float w[3], s1 = 0.f, s2 = 0.f;
#pragma unroll
    for (int j = 0; j < 3; ++j) {
        w[j] = rv[j] + xv[j];
        s1 += w[j]; s2 += w[j] * w[j];
    }
    block_reduce2(s1, s2, sm, tid);
    float m = s1 * (1.f / DM);
    float inv = rsqrtf(s2 * (1.f / DM) - m * m + 1e-12f);
#pragma unroll
    for (int j = 0; j < 3; ++j) {
        int c = j * 256 + tid;
        out[(size_t)t * DM + c] = (w[j] - m) * inv * out_g[c] + out_b[c];
    }
}

// ---------------- launcher ----------------
extern "C" void kernel_launch(void* const* d_in, const int* in_sizes, int n_in,
                              void* d_out, int out_size, void* d_ws, size_t ws_size,
                              hipStream_t stream) {
    if (ws_size < (size_t)WS_END) return;

    const float* X     = (const float*)d_in[0];
    const int*   type  = (const int*)d_in[1];
    const float* W1    = (const float*)d_in[2];
    const float* b1    = (const float*)d_in[3];
    const float* W2    = (const float*)d_in[4];
    const float* b2    = (const float*)d_in[5];
    const float* ln_g  = (const float*)d_in[6];
    const float* ln_b  = (const float*)d_in[7];
    const float* out_g = (const float*)d_in[8];
    const float* out_b = (const float*)d_in[9];
    float* out = (float*)d_out;

    char* ws = (char*)d_ws;
    int* cnt    = (int*)(ws + WS_CNT);
    int* bases  = (int*)(ws + WS_BASES);
    int* pos_of = (int*)(ws + WS_POS);
    int* list   = (int*)(ws + WS_LIST);
    ushort* Xb  = (ushort*)(ws + WS_XB);
    ushort* W1t = (ushort*)(ws + WS_W1T);
    ushort* W2t = (ushort*)(ws + WS_W2T);
    ushort* h1  = (ushort*)(ws + WS_H1);
    ushort* h2  = (ushort*)(ws + WS_H2);

    hipMemsetAsync(cnt, 0, NEXP * sizeof(int), stream);   // routing counters
    prep_kernel<<<PREP_BLKS, 256, 0, stream>>>(type, X, W1, W2,
                                               cnt, pos_of, list, Xb, W1t, W2t);
    scan_kernel<<<1, 64, 0, stream>>>(cnt, bases);
    gemm1_kernel<<<dim3(24, 132), 512, 0, stream>>>(Xb, W1t, b1, cnt, bases, list, h1);
    gemm2_kernel<<<dim3(6, 132), 512, 0, stream>>>(h1, W2t, b2, cnt, bases, h2);
    finalize_kernel<<<NTOK, 256, 0, stream>>>(X, type, pos_of, bases, h2, ln_g, ln_b, out_g, out_b, out);
}

// Round 6
// 379.009 us; speedup vs baseline: 1.2248x; 1.0170x over previous
//
#include <hip/hip_runtime.h>
#include <hip/hip_bf16.h>
#include <math.h>

#define NTOK   16384
#define DM     768
#define DF     3072
#define NEXP   4

// prep kernel fat-grid sections (fewer, fatter blocks: dispatch-rate fix)
#define RBLKS  64                      // routing: NTOK/256 tokens per block
#define XBLKS  768                     // X cvt: 8 units of 2048 elems each
#define WBLKS  288                     // per-W transpose: 8 tiles of 64x64 each
#define PREP_BLKS (RBLKS + XBLKS + 2 * WBLKS)   // 1408

typedef short bf16x8 __attribute__((ext_vector_type(8)));
typedef float f32x4  __attribute__((ext_vector_type(4)));

// ---------------- workspace layout (bytes) ----------------
#define WS_CNT    0u
#define WS_BASES  256u                        // bases[4] + panel offsets (ints)
#define WS_POS    512u                        // NTOK ints            = 65536
#define WS_LIST   (512u + 65536u)             // NEXP*NTOK ints       = 262144
#define WS_XB     (WS_LIST + 262144u)         // NTOK*DM bf16         = 25165824
#define WS_W1T    (WS_XB + 25165824u)         // 4*DF*DM bf16         = 18874368
#define WS_W2T    (WS_W1T + 18874368u)        // 4*DM*DF bf16         = 18874368
#define WS_H1     (WS_W2T + 18874368u)        // NTOK*DF bf16         = 100663296
#define WS_H2     (WS_H1 + 100663296u)        // NTOK*DM bf16         = 25165824
#define WS_END    (WS_H2 + 25165824u)

// ---------------- bf16 helpers (manual, RNE) ----------------
__device__ __forceinline__ ushort f2bf(float f) {
    unsigned int v; __builtin_memcpy(&v, &f, 4);
    v = v + 0x7fffu + ((v >> 16) & 1u);
    return (ushort)(v >> 16);
}
__device__ __forceinline__ float bf2f(ushort u) {
    unsigned int v = ((unsigned int)u) << 16;
    float f; __builtin_memcpy(&f, &v, 4); return f;
}

// fast gelu: x * sigmoid(1.5957691(x + 0.044715 x^3)); exp2-based, ~1e-3 abs err
__device__ __forceinline__ float fast_gelu(float v) {
    float y = v + 0.044715f * v * v * v;
    float e = __builtin_amdgcn_exp2f(-2.3022082f * y);
    return v * __builtin_amdgcn_rcpf(1.0f + e);
}

// async global->LDS, 16B per lane. LDS dest must be uniform_base + lane*16.
typedef __attribute__((address_space(1))) const void gvoid_t;
typedef __attribute__((address_space(3))) void lvoid_t;
__device__ __forceinline__ void cp16(const void* g, void* l) {
    __builtin_amdgcn_global_load_lds((gvoid_t*)g, (lvoid_t*)l, 16, 0, 0);
}

// bijective chunked XCD remap over T active blocks (m204 formula)
__device__ __forceinline__ int xcd_remap(int id, int T) {
    const int q = T >> 3, r = T & 7;
    const int x = id & 7, j = id >> 3;
    return (x < r ? x * (q + 1) : r * (q + 1) + (x - r) * q) + j;
}

// ---------------- transpose tile helper ----------------
__device__ __forceinline__ void transpose_tile(
    const float* __restrict__ src, ushort* __restrict__ dst, int R, int C,
    int bx, int by, int tid, ushort* tile /* [64][72] */) {
    const int r0 = by * 64, c0 = bx * 64;
#pragma unroll
    for (int q = 0; q < 2; ++q) {
        int li = q * 256 + tid;
        int r = li >> 3, c = (li & 7) * 8;
        const float* s = src + (size_t)(r0 + r) * C + (c0 + c);
        float4 v0 = *(const float4*)s;
        float4 v1 = *(const float4*)(s + 4);
        ushort tmp[8];
        tmp[0] = f2bf(v0.x); tmp[1] = f2bf(v0.y); tmp[2] = f2bf(v0.z); tmp[3] = f2bf(v0.w);
        tmp[4] = f2bf(v1.x); tmp[5] = f2bf(v1.y); tmp[6] = f2bf(v1.z); tmp[7] = f2bf(v1.w);
        int sw = (((c >> 3) ^ ((r >> 3) & 7)) << 3);
        *(uint4*)&tile[r * 72 + sw] = *(uint4*)tmp;
    }
    __syncthreads();
#pragma unroll
    for (int q = 0; q < 2; ++q) {
        int li = q * 256 + tid;
        int r = li >> 3, c = (li & 7) * 8;
        ushort tmp[8];
#pragma unroll
        for (int j = 0; j < 8; ++j)
            tmp[j] = tile[(c + j) * 72 +
                          ((((r >> 3) & 7) ^ (((c + j) >> 3) & 7)) << 3) + (r & 7)];
        *(uint4*)(dst + (size_t)(c0 + r) * R + (r0 + c)) = *(uint4*)tmp;
    }
}

// ---------------- prep: parallel routing + X cvt + W1/W2 transpose ----------------
__global__ __launch_bounds__(256) void prep_kernel(
    const int* __restrict__ type_seq, const float* __restrict__ X,
    const float* __restrict__ W1, const float* __restrict__ W2,
    int* __restrict__ cnt,
    int* __restrict__ pos_of, int* __restrict__ list,
    ushort* __restrict__ Xb, ushort* __restrict__ W1t, ushort* __restrict__ W2t) {
    __shared__ ushort tile[64 * 72];
    __shared__ int lcnt[NEXP];
    __shared__ int lbase[NEXP];
    const int tid = threadIdx.x;
    const int bid = blockIdx.x;

    if (bid < RBLKS) {
        // ---- parallel routing: this block owns tokens [bid*256, bid*256+256) ----
        if (tid < NEXP) lcnt[tid] = 0;
        __syncthreads();
        const int lane = tid & 63;
        const int t = bid * 256 + tid;
        const int k = type_seq[t];
        int my_e = -1, my_p = 0;
#pragma unroll
        for (int e = 0; e < NEXP; ++e) {
            unsigned long long m = __ballot(k == e + 1);
            int total = __popcll(m);
            int b = 0;
            if (lane == 0 && total) b = atomicAdd(&lcnt[e], total);
            b = __shfl(b, 0, 64);
            if (k == e + 1) {
                my_e = e;
                my_p = b + __popcll(m & ((1ull << lane) - 1ull));
            }
        }
        __syncthreads();
        if (tid < NEXP && lcnt[tid] > 0)
            lbase[tid] = atomicAdd(&cnt[tid], lcnt[tid]);   // global, device-scope
        __syncthreads();
        if (my_e >= 0) {
            int gp = lbase[my_e] + my_p;
            list[my_e * NTOK + gp] = t;
            pos_of[t] = gp;
        }
        return;
    }

    int id = bid - RBLKS;
    if (id < XBLKS) {
        // ---- X fp32 -> bf16, 8 batched units per block ----
        size_t ibase = ((size_t)id * 8 * 256 + tid) * 8;
        float4 va[8], vb[8];
#pragma unroll
        for (int k = 0; k < 8; ++k) {
            va[k] = *(const float4*)(X + ibase + (size_t)k * 2048);
            vb[k] = *(const float4*)(X + ibase + (size_t)k * 2048 + 4);
        }
#pragma unroll
        for (int k = 0; k < 8; ++k) {
            ushort tmp[8];
            tmp[0] = f2bf(va[k].x); tmp[1] = f2bf(va[k].y);
            tmp[2] = f2bf(va[k].z); tmp[3] = f2bf(va[k].w);
            tmp[4] = f2bf(vb[k].x); tmp[5] = f2bf(vb[k].y);
            tmp[6] = f2bf(vb[k].z); tmp[7] = f2bf(vb[k].w);
            *(uint4*)(Xb + ibase + (size_t)k * 2048) = *(uint4*)tmp;
        }
        return;
    }
    id -= XBLKS;
    if (id < WBLKS) {
#pragma unroll 1
        for (int k = 0; k < 8; ++k) {
            int tt = id * 8 + k;
            int z = tt / 576, rr = tt % 576;
            size_t mb = (size_t)z * DM * DF;
            transpose_tile(W1 + mb, W1t + mb, DM, DF, rr % 48, rr / 48, tid, tile);
            __syncthreads();
        }
        return;
    }
    id -= WBLKS;
    {
#pragma unroll 1
        for (int k = 0; k < 8; ++k) {
            int tt = id * 8 + k;
            int z = tt / 576, rr = tt % 576;
            size_t mb = (size_t)z * DF * DM;
            transpose_tile(W2 + mb, W2t + mb, DF, DM, rr % 12, rr / 12, tid, tile);
            __syncthreads();
        }
    }
}

// ---------------- scan: bases + 128-row panel offsets from cnt ----------------
__global__ __launch_bounds__(64) void scan_kernel(
    const int* __restrict__ cnt, int* __restrict__ bases) {
    if (threadIdx.x == 0) {
        int s = 0, mb = 0;
        for (int e = 0; e < NEXP; ++e) {
            bases[e] = s;
            bases[8 + e] = mb;
            s += cnt[e];
            mb += (cnt[e] + 127) >> 7;
        }
        bases[12] = mb;
    }
}

// =====================================================================
// GEMM structure (both kernels, verified round-4/5 best):
// 512 threads = 8 waves, tile 128x128, BK=32, per-wave 64x32 output.
// TRIPLE-buffered LDS (48 KiB), prefetch depth 2, counted
// s_waitcnt vmcnt(2) + raw s_barrier (T4); vmcnt(0) only at the last
// iteration. sched_barrier(0) fences pin ordering (rule #18).
// k-quad XOR swizzle (T2, both-sides, conflict-free). XCD remap (T1).
// =====================================================================

__global__ __launch_bounds__(512, 4) void gemm1_kernel(
    const ushort* __restrict__ Xb, const ushort* __restrict__ W1t,
    const float* __restrict__ b1, const int* __restrict__ cnt,
    const int* __restrict__ bases, const int* __restrict__ list,
    ushort* __restrict__ h1) {
    const int mb = bases[12];
    const int T = mb * 24;
    int id = blockIdx.y * 24 + blockIdx.x;
    if (id >= T) return;
    id = xcd_remap(id, T);
    const int y = id / 24;
    const int n0 = (id % 24) * 128;
    const int* mboff = bases + 8;
    const int e = (y >= mboff[1]) + (y >= mboff[2]) + (y >= mboff[3]);
    const int m0 = (y - mboff[e]) << 7;
    const int count = cnt[e];
    const int NK = DM / 32;   // 24

    __shared__ __align__(16) short As[3][4096];
    __shared__ __align__(16) short Bs[3][4096];

    const int tid = threadIdx.x;
    const int wave = tid >> 6, lane = tid & 63;
    const int wm = (wave & 1) * 64, wn = (wave >> 1) * 32;
    const int lrow = lane & 15;
    const int qg = lane >> 4;

    int r0 = min(m0 + (tid >> 2), count - 1);
    int t0 = list[e * NTOK + r0];
    const int qsrc = ((tid & 3) ^ ((tid >> 3) & 3)) * 8;   // source k-quad pre-swizzle
    const ushort* a0 = Xb + (size_t)t0 * DM + qsrc;
    const ushort* Wb = W1t + (size_t)e * DF * DM;
    const ushort* bp0 = Wb + (size_t)(n0 + (tid >> 2)) * DM + qsrc;

    int aOff[4], bOff[2];
#pragma unroll
    for (int i = 0; i < 4; ++i) {
        int ra = wm + i * 16 + lrow;
        aOff[i] = ra * 32 + (qg ^ ((ra >> 1) & 3)) * 8;
    }
#pragma unroll
    for (int j = 0; j < 2; ++j) {
        int rb = wn + j * 16 + lrow;
        bOff[j] = rb * 32 + (qg ^ ((rb >> 1) & 3)) * 8;
    }

    f32x4 z = {0.f, 0.f, 0.f, 0.f};
    f32x4 acc[4][2];
#pragma unroll
    for (int i = 0; i < 4; ++i)
#pragma unroll
        for (int j = 0; j < 2; ++j) acc[i][j] = z;

    auto STAGE = [&](int wb) {
        cp16(a0, &As[0][0] + wb * 4096 + tid * 8);
        cp16(bp0, &Bs[0][0] + wb * 4096 + tid * 8);
        a0 += 32; bp0 += 32;
    };

    STAGE(0); STAGE(1);                         // depth-2 prologue, 4 cp16 in flight
    int rb = 0;
    for (int ks = 0; ks < NK; ++ks) {
        __builtin_amdgcn_sched_barrier(0);
        if (ks + 1 < NK) { asm volatile("s_waitcnt vmcnt(2)" ::: "memory"); }
        else             { asm volatile("s_waitcnt vmcnt(0)" ::: "memory"); }
        __builtin_amdgcn_s_barrier();
        __builtin_amdgcn_sched_barrier(0);
        if (ks + 2 < NK) {
            int wb = rb - 1; if (wb < 0) wb += 3;   // (ks+2)%3
            STAGE(wb);
        }
        const short* Ab = &As[0][0] + rb * 4096;
        const short* Bb = &Bs[0][0] + rb * 4096;
        bf16x8 av[4], bv[2];
#pragma unroll
        for (int i = 0; i < 4; ++i) av[i] = *(const bf16x8*)(Ab + aOff[i]);
#pragma unroll
        for (int j = 0; j < 2; ++j) bv[j] = *(const bf16x8*)(Bb + bOff[j]);
#pragma unroll
        for (int i = 0; i < 4; ++i)
#pragma unroll
            for (int j = 0; j < 2; ++j)
                acc[i][j] = __builtin_amdgcn_mfma_f32_16x16x32_bf16(av[i], bv[j], acc[i][j], 0, 0, 0);
        rb = (rb + 1 == 3) ? 0 : rb + 1;
    }

    const int base = bases[e];
    float bias[2];
#pragma unroll
    for (int nt = 0; nt < 2; ++nt)
        bias[nt] = b1[e * DF + n0 + wn + nt * 16 + lrow];
#pragma unroll
    for (int mt = 0; mt < 4; ++mt) {
        int gm = m0 + wm + mt * 16 + (lane >> 4) * 4;
#pragma unroll
        for (int nt = 0; nt < 2; ++nt) {
            int gn = n0 + wn + nt * 16 + lrow;
#pragma unroll
            for (int r = 0; r < 4; ++r) {
                int i = gm + r;
                if (i < count) {
                    float v = acc[mt][nt][r] + bias[nt];
                    h1[(size_t)(base + i) * DF + gn] = f2bf(fast_gelu(v));
                }
            }
        }
    }
}

__global__ __launch_bounds__(512, 4) void gemm2_kernel(
    const ushort* __restrict__ h1, const ushort* __restrict__ W2t,
    const float* __restrict__ b2, const int* __restrict__ cnt,
    const int* __restrict__ bases, ushort* __restrict__ h2) {
    const int mb = bases[12];
    const int T = mb * 6;
    int id = blockIdx.y * 6 + blockIdx.x;
    if (id >= T) return;
    id = xcd_remap(id, T);
    const int y = id / 6;
    const int n0 = (id % 6) * 128;
    const int* mboff = bases + 8;
    const int e = (y >= mboff[1]) + (y >= mboff[2]) + (y >= mboff[3]);
    const int m0 = (y - mboff[e]) << 7;
    const int count = cnt[e];
    const int base = bases[e];
    const int NK = DF / 32;   // 96

    __shared__ __align__(16) short As[3][4096];
    __shared__ __align__(16) short Bs[3][4096];

    const int tid = threadIdx.x;
    const int wave = tid >> 6, lane = tid & 63;
    const int wm = (wave & 1) * 64, wn = (wave >> 1) * 32;
    const int lrow = lane & 15;
    const int qg = lane >> 4;

    int r0 = min(m0 + (tid >> 2), count - 1);
    const int qsrc = ((tid & 3) ^ ((tid >> 3) & 3)) * 8;
    const ushort* a0 = h1 + (size_t)(base + r0) * DF + qsrc;
    const ushort* Wb = W2t + (size_t)e * DM * DF;
    const ushort* bp0 = Wb + (size_t)(n0 + (tid >> 2)) * DF + qsrc;

    int aOff[4], bOff[2];
#pragma unroll
    for (int i = 0; i < 4; ++i) {
        int ra = wm + i * 16 + lrow;
        aOff[i] = ra * 32 + (qg ^ ((ra >> 1) & 3)) * 8;
    }
#pragma unroll
    for (int j = 0; j < 2; ++j) {
        int rb = wn + j * 16 + lrow;
        bOff[j] = rb * 32 + (qg ^ ((rb >> 1) & 3)) * 8;
    }

    f32x4 z = {0.f, 0.f, 0.f, 0.f};
    f32x4 acc[4][2];
#pragma unroll
    for (int i = 0; i < 4; ++i)
#pragma unroll
        for (int j = 0; j < 2; ++j) acc[i][j] = z;

    auto STAGE = [&](int wb) {
        cp16(a0, &As[0][0] + wb * 4096 + tid * 8);
        cp16(bp0, &Bs[0][0] + wb * 4096 + tid * 8);
        a0 += 32; bp0 += 32;
    };

    STAGE(0); STAGE(1);
    int rb = 0;
    for (int ks = 0; ks < NK; ++ks) {
        __builtin_amdgcn_sched_barrier(0);
        if (ks + 1 < NK) { asm volatile("s_waitcnt vmcnt(2)" ::: "memory"); }
        else             { asm volatile("s_waitcnt vmcnt(0)" ::: "memory"); }
        __builtin_amdgcn_s_barrier();
        __builtin_amdgcn_sched_barrier(0);
        if (ks + 2 < NK) {
            int wb = rb - 1; if (wb < 0) wb += 3;
            STAGE(wb);
        }
        const short* Ab = &As[0][0] + rb * 4096;
        const short* Bb = &Bs[0][0] + rb * 4096;
        bf16x8 av[4], bv[2];
#pragma unroll
        for (int i = 0; i < 4; ++i) av[i] = *(const bf16x8*)(Ab + aOff[i]);
#pragma unroll
        for (int j = 0; j < 2; ++j) bv[j] = *(const bf16x8*)(Bb + bOff[j]);
#pragma unroll
        for (int i = 0; i < 4; ++i)
#pragma unroll
            for (int j = 0; j < 2; ++j)
                acc[i][j] = __builtin_amdgcn_mfma_f32_16x16x32_bf16(av[i], bv[j], acc[i][j], 0, 0, 0);
        rb = (rb + 1 == 3) ? 0 : rb + 1;
    }

    float bias[2];
#pragma unroll
    for (int nt = 0; nt < 2; ++nt)
        bias[nt] = b2[e * DM + n0 + wn + nt * 16 + lrow];
#pragma unroll
    for (int mt = 0; mt < 4; ++mt) {
        int gm = m0 + wm + mt * 16 + (lane >> 4) * 4;
#pragma unroll
        for (int nt = 0; nt < 2; ++nt) {
            int gn = n0 + wn + nt * 16 + lrow;
#pragma unroll
            for (int r = 0; r < 4; ++r) {
                int i = gm + r;
                if (i < count)
                    h2[(size_t)(base + i) * DM + gn] = f2bf(acc[mt][nt][r] + bias[nt]);
            }
        }
    }
}

// ---------------- finalize: 8 tokens/block, one WAVE per token ----------------
// 2048 blocks x 256 thr; wave w handles tokens blk*8+2w, blk*8+2w+1.
// k=type_seq[t] is wave-uniform -> no divergence. Reductions are pure
// __shfl_xor butterflies over 64 lanes (no LDS, no __syncthreads).
// 12 elems/lane; all loads vectorized (float4 / ushort4).
__global__ __launch_bounds__(256) void finalize_kernel(
    const float* __restrict__ X, const int* __restrict__ type_seq,
    const int* __restrict__ pos_of, const int* __restrict__ bases,
    const ushort* __restrict__ h2,
    const float* __restrict__ ln_g, const float* __restrict__ ln_b,
    const float* __restrict__ out_g, const float* __restrict__ out_b,
    float* __restrict__ out) {
    const int tid = threadIdx.x;
    const int wave = tid >> 6, lane = tid & 63;
    const int col0 = lane * 4;

#pragma unroll 1
    for (int ti = 0; ti < 2; ++ti) {
        const int t = blockIdx.x * 8 + wave * 2 + ti;
        const int k = type_seq[t];

        const float* Xr = X + (size_t)t * DM;
        float4 xv[3];
#pragma unroll
        for (int j = 0; j < 3; ++j) xv[j] = *(const float4*)(Xr + col0 + j * 256);

        float rv[12];
        if (k > 0) {
            const int e = k - 1;
            const size_t row = (size_t)(bases[e] + pos_of[t]);
            const ushort* hr = h2 + row * DM;
            float v[12];
            float s1 = 0.f, s2 = 0.f;
#pragma unroll
            for (int j = 0; j < 3; ++j) {
                ushort4 hv = *(const ushort4*)(hr + col0 + j * 256);
                float f0 = bf2f(hv.x) + xv[j].x;
                float f1 = bf2f(hv.y) + xv[j].y;
                float f2 = bf2f(hv.z) + xv[j].z;
                float f3 = bf2f(hv.w) + xv[j].w;
                v[j * 4 + 0] = f0; v[j * 4 + 1] = f1;
                v[j * 4 + 2] = f2; v[j * 4 + 3] = f3;
                s1 += (f0 + f1) + (f2 + f3);
                s2 += (f0 * f0 + f1 * f1) + (f2 * f2 + f3 * f3);
            }
#pragma unroll
            for (int off = 32; off > 0; off >>= 1) {
                s1 += __shfl_xor(s1, off, 64);
                s2 += __shfl_xor(s2, off, 64);
            }
            float m = s1 * (1.f / DM);
            float inv = rsqrtf(s2 * (1.f / DM) - m * m + 1e-12f);
#pragma unroll
            for (int j = 0; j < 3; ++j) {
                float4 g = *(const float4*)(ln_g + e * DM + col0 + j * 256);
                float4 b = *(const float4*)(ln_b + e * DM + col0 + j * 256);
                rv[j * 4 + 0] = (v[j * 4 + 0] - m) * inv * g.x + b.x;
                rv[j * 4 + 1] = (v[j * 4 + 1] - m) * inv * g.y + b.y;
                rv[j * 4 + 2] = (v[j * 4 + 2] - m) * inv * g.z + b.z;
                rv[j * 4 + 3] = (v[j * 4 + 3] - m) * inv * g.w + b.w;
            }
        } else {
#pragma unroll
            for (int j = 0; j < 12; ++j) rv[j] = 0.f;
        }

        float w[12];
        float s1 = 0.f, s2 = 0.f;
#pragma unroll
        for (int j = 0; j < 3; ++j) {
            float f0 = rv[j * 4 + 0] + xv[j].x;
            float f1 = rv[j * 4 + 1] + xv[j].y;
            float f2 = rv[j * 4 + 2] + xv[j].z;
            float f3 = rv[j * 4 + 3] + xv[j].w;
            w[j * 4 + 0] = f0; w[j * 4 + 1] = f1;
            w[j * 4 + 2] = f2; w[j * 4 + 3] = f3;
            s1 += (f0 + f1) + (f2 + f3);
            s2 += (f0 * f0 + f1 * f1) + (f2 * f2 + f3 * f3);
        }
#pragma unroll
        for (int off = 32; off > 0; off >>= 1) {
            s1 += __shfl_xor(s1, off, 64);
            s2 += __shfl_xor(s2, off, 64);
        }
        float m = s1 * (1.f / DM);
        float inv = rsqrtf(s2 * (1.f / DM) - m * m + 1e-12f);
#pragma unroll
        for (int j = 0; j < 3; ++j) {
            float4 g = *(const float4*)(out_g + col0 + j * 256);
            float4 b = *(const float4*)(out_b + col0 + j * 256);
            float4 o;
            o.x = (w[j * 4 + 0] - m) * inv * g.x + b.x;
            o.y = (w[j * 4 + 1] - m) * inv * g.y + b.y;
            o.z = (w[j * 4 + 2] - m) * inv * g.z + b.z;
            o.w = (w[j * 4 + 3] - m) * inv * g.w + b.w;
            *(float4*)(out + (size_t)t * DM + col0 + j * 256) = o;
        }
    }
}

// ---------------- launcher ----------------
extern "C" void kernel_launch(void* const* d_in, const int* in_sizes, int n_in,
                              void* d_out, int out_size, void* d_ws, size_t ws_size,
                              hipStream_t stream) {
    if (ws_size < (size_t)WS_END) return;

    const float* X     = (const float*)d_in[0];
    const int*   type  = (const int*)d_in[1];
    const float* W1    = (const float*)d_in[2];
    const float* b1    = (const float*)d_in[3];
    const float* W2    = (const float*)d_in[4];
    const float* b2    = (const float*)d_in[5];
    const float* ln_g  = (const float*)d_in[6];
    const float* ln_b  = (const float*)d_in[7];
    const float* out_g = (const float*)d_in[8];
    const float* out_b = (const float*)d_in[9];
    float* out = (float*)d_out;

    char* ws = (char*)d_ws;
    int* cnt    = (int*)(ws + WS_CNT);
    int* bases  = (int*)(ws + WS_BASES);
    int* pos_of = (int*)(ws + WS_POS);
    int* list   = (int*)(ws + WS_LIST);
    ushort* Xb  = (ushort*)(ws + WS_XB);
    ushort* W1t = (ushort*)(ws + WS_W1T);
    ushort* W2t = (ushort*)(ws + WS_W2T);
    ushort* h1  = (ushort*)(ws + WS_H1);
    ushort* h2  = (ushort*)(ws + WS_H2);

    hipMemsetAsync(cnt, 0, NEXP * sizeof(int), stream);   // routing counters
    prep_kernel<<<PREP_BLKS, 256, 0, stream>>>(type, X, W1, W2,
                                               cnt, pos_of, list, Xb, W1t, W2t);
    scan_kernel<<<1, 64, 0, stream>>>(cnt, bases);
    gemm1_kernel<<<dim3(24, 132), 512, 0, stream>>>(Xb, W1t, b1, cnt, bases, list, h1);
    gemm2_kernel<<<dim3(6, 132), 512, 0, stream>>>(h1, W2t, b2, cnt, bases, h2);
    finalize_kernel<<<NTOK / 8, 256, 0, stream>>>(X, type, pos_of, bases, h2, ln_g, ln_b, out_g, out_b, out);
}

// Round 7
// 378.952 us; speedup vs baseline: 1.2249x; 1.0002x over previous
//
#include <hip/hip_runtime.h>
#include <hip/hip_bf16.h>
#include <math.h>

#define NTOK   16384
#define DM     768
#define DF     3072
#define NEXP   4

// prep kernel fat-grid sections (fewer, fatter blocks: dispatch-rate fix)
#define RBLKS  64                      // routing: NTOK/256 tokens per block
#define XBLKS  768                     // X cvt: 8 units of 2048 elems each
#define WBLKS  288                     // per-W transpose: 8 tiles of 64x64 each
#define PREP_BLKS (RBLKS + XBLKS + 2 * WBLKS)   // 1408

typedef short bf16x8 __attribute__((ext_vector_type(8)));
typedef float f32x4  __attribute__((ext_vector_type(4)));

// ---------------- workspace layout (bytes) ----------------
#define WS_CNT    0u
#define WS_BASES  256u                        // bases[4] + panel offsets (ints)
#define WS_POS    512u                        // NTOK ints            = 65536
#define WS_LIST   (512u + 65536u)             // NEXP*NTOK ints       = 262144
#define WS_XB     (WS_LIST + 262144u)         // NTOK*DM bf16         = 25165824
#define WS_W1T    (WS_XB + 25165824u)         // 4*DF*DM bf16         = 18874368
#define WS_W2T    (WS_W1T + 18874368u)        // 4*DM*DF bf16         = 18874368
#define WS_H1     (WS_W2T + 18874368u)        // NTOK*DF bf16         = 100663296
#define WS_H2     (WS_H1 + 100663296u)        // NTOK*DM bf16         = 25165824
#define WS_END    (WS_H2 + 25165824u)

// ---------------- bf16 helpers (manual, RNE) ----------------
__device__ __forceinline__ ushort f2bf(float f) {
    unsigned int v; __builtin_memcpy(&v, &f, 4);
    v = v + 0x7fffu + ((v >> 16) & 1u);
    return (ushort)(v >> 16);
}
__device__ __forceinline__ float bf2f(ushort u) {
    unsigned int v = ((unsigned int)u) << 16;
    float f; __builtin_memcpy(&f, &v, 4); return f;
}

// fast gelu: x * sigmoid(1.5957691(x + 0.044715 x^3)); exp2-based, ~1e-3 abs err
__device__ __forceinline__ float fast_gelu(float v) {
    float y = v + 0.044715f * v * v * v;
    float e = __builtin_amdgcn_exp2f(-2.3022082f * y);
    return v * __builtin_amdgcn_rcpf(1.0f + e);
}

// async global->LDS, 16B per lane. LDS dest must be uniform_base + lane*16.
typedef __attribute__((address_space(1))) const void gvoid_t;
typedef __attribute__((address_space(3))) void lvoid_t;
__device__ __forceinline__ void cp16(const void* g, void* l) {
    __builtin_amdgcn_global_load_lds((gvoid_t*)g, (lvoid_t*)l, 16, 0, 0);
}

// bijective chunked XCD remap over T active blocks (m204 formula)
__device__ __forceinline__ int xcd_remap(int id, int T) {
    const int q = T >> 3, r = T & 7;
    const int x = id & 7, j = id >> 3;
    return (x < r ? x * (q + 1) : r * (q + 1) + (x - r) * q) + j;
}

// ---------------- transpose tile helper ----------------
__device__ __forceinline__ void transpose_tile(
    const float* __restrict__ src, ushort* __restrict__ dst, int R, int C,
    int bx, int by, int tid, ushort* tile /* [64][72] */) {
    const int r0 = by * 64, c0 = bx * 64;
#pragma unroll
    for (int q = 0; q < 2; ++q) {
        int li = q * 256 + tid;
        int r = li >> 3, c = (li & 7) * 8;
        const float* s = src + (size_t)(r0 + r) * C + (c0 + c);
        float4 v0 = *(const float4*)s;
        float4 v1 = *(const float4*)(s + 4);
        ushort tmp[8];
        tmp[0] = f2bf(v0.x); tmp[1] = f2bf(v0.y); tmp[2] = f2bf(v0.z); tmp[3] = f2bf(v0.w);
        tmp[4] = f2bf(v1.x); tmp[5] = f2bf(v1.y); tmp[6] = f2bf(v1.z); tmp[7] = f2bf(v1.w);
        int sw = (((c >> 3) ^ ((r >> 3) & 7)) << 3);
        *(uint4*)&tile[r * 72 + sw] = *(uint4*)tmp;
    }
    __syncthreads();
#pragma unroll
    for (int q = 0; q < 2; ++q) {
        int li = q * 256 + tid;
        int r = li >> 3, c = (li & 7) * 8;
        ushort tmp[8];
#pragma unroll
        for (int j = 0; j < 8; ++j)
            tmp[j] = tile[(c + j) * 72 +
                          ((((r >> 3) & 7) ^ (((c + j) >> 3) & 7)) << 3) + (r & 7)];
        *(uint4*)(dst + (size_t)(c0 + r) * R + (r0 + c)) = *(uint4*)tmp;
    }
}

// ---------------- prep: parallel routing + X cvt + W1/W2 transpose ----------------
__global__ __launch_bounds__(256) void prep_kernel(
    const int* __restrict__ type_seq, const float* __restrict__ X,
    const float* __restrict__ W1, const float* __restrict__ W2,
    int* __restrict__ cnt,
    int* __restrict__ pos_of, int* __restrict__ list,
    ushort* __restrict__ Xb, ushort* __restrict__ W1t, ushort* __restrict__ W2t) {
    __shared__ ushort tile[64 * 72];
    __shared__ int lcnt[NEXP];
    __shared__ int lbase[NEXP];
    const int tid = threadIdx.x;
    const int bid = blockIdx.x;

    if (bid < RBLKS) {
        // ---- parallel routing: this block owns tokens [bid*256, bid*256+256) ----
        if (tid < NEXP) lcnt[tid] = 0;
        __syncthreads();
        const int lane = tid & 63;
        const int t = bid * 256 + tid;
        const int k = type_seq[t];
        int my_e = -1, my_p = 0;
#pragma unroll
        for (int e = 0; e < NEXP; ++e) {
            unsigned long long m = __ballot(k == e + 1);
            int total = __popcll(m);
            int b = 0;
            if (lane == 0 && total) b = atomicAdd(&lcnt[e], total);
            b = __shfl(b, 0, 64);
            if (k == e + 1) {
                my_e = e;
                my_p = b + __popcll(m & ((1ull << lane) - 1ull));
            }
        }
        __syncthreads();
        if (tid < NEXP && lcnt[tid] > 0)
            lbase[tid] = atomicAdd(&cnt[tid], lcnt[tid]);   // global, device-scope
        __syncthreads();
        if (my_e >= 0) {
            int gp = lbase[my_e] + my_p;
            list[my_e * NTOK + gp] = t;
            pos_of[t] = gp;
        }
        return;
    }

    int id = bid - RBLKS;
    if (id < XBLKS) {
        // ---- X fp32 -> bf16, 8 batched units per block ----
        size_t ibase = ((size_t)id * 8 * 256 + tid) * 8;
        float4 va[8], vb[8];
#pragma unroll
        for (int k = 0; k < 8; ++k) {
            va[k] = *(const float4*)(X + ibase + (size_t)k * 2048);
            vb[k] = *(const float4*)(X + ibase + (size_t)k * 2048 + 4);
        }
#pragma unroll
        for (int k = 0; k < 8; ++k) {
            ushort tmp[8];
            tmp[0] = f2bf(va[k].x); tmp[1] = f2bf(va[k].y);
            tmp[2] = f2bf(va[k].z); tmp[3] = f2bf(va[k].w);
            tmp[4] = f2bf(vb[k].x); tmp[5] = f2bf(vb[k].y);
            tmp[6] = f2bf(vb[k].z); tmp[7] = f2bf(vb[k].w);
            *(uint4*)(Xb + ibase + (size_t)k * 2048) = *(uint4*)tmp;
        }
        return;
    }
    id -= XBLKS;
    if (id < WBLKS) {
#pragma unroll 1
        for (int k = 0; k < 8; ++k) {
            int tt = id * 8 + k;
            int z = tt / 576, rr = tt % 576;
            size_t mb = (size_t)z * DM * DF;
            transpose_tile(W1 + mb, W1t + mb, DM, DF, rr % 48, rr / 48, tid, tile);
            __syncthreads();
        }
        return;
    }
    id -= WBLKS;
    {
#pragma unroll 1
        for (int k = 0; k < 8; ++k) {
            int tt = id * 8 + k;
            int z = tt / 576, rr = tt % 576;
            size_t mb = (size_t)z * DF * DM;
            transpose_tile(W2 + mb, W2t + mb, DF, DM, rr % 12, rr / 12, tid, tile);
            __syncthreads();
        }
    }
}

// ---------------- scan: bases + 128-row panel offsets from cnt ----------------
__global__ __launch_bounds__(64) void scan_kernel(
    const int* __restrict__ cnt, int* __restrict__ bases) {
    if (threadIdx.x == 0) {
        int s = 0, mb = 0;
        for (int e = 0; e < NEXP; ++e) {
            bases[e] = s;
            bases[8 + e] = mb;
            s += cnt[e];
            mb += (cnt[e] + 127) >> 7;
        }
        bases[12] = mb;
    }
}

// =====================================================================
// GEMM structure: per-wave 64x64 output (16 MFMA : 8 ds_read_b128 per
// K-step), BK=32, TRIPLE-buffered LDS, prefetch depth 2 with counted
// s_waitcnt vmcnt(N) + raw s_barrier (T4, verified R4); vmcnt(0) only
// at the last iteration. sched_barrier(0) pins ordering (rule #18).
// k-quad XOR swizzle key=(row>>1)&3 (T2, both-sides, conflict-free,
// commutes with +64/+128 row offsets). XCD remap (T1).
//   gemm1: tile 128x256, 8 waves (2Mx4N), LDS 72 KiB, 3 cp16/thr/tile
//   gemm2: tile 128x128, 4 waves (2Mx2N), LDS 48 KiB, 4 cp16/thr/tile
// =====================================================================

__global__ __launch_bounds__(512, 4) void gemm1_kernel(
    const ushort* __restrict__ Xb, const ushort* __restrict__ W1t,
    const float* __restrict__ b1, const int* __restrict__ cnt,
    const int* __restrict__ bases, const int* __restrict__ list,
    ushort* __restrict__ h1) {
    const int mb = bases[12];
    const int T = mb * 12;
    int id = blockIdx.y * 12 + blockIdx.x;
    if (id >= T) return;
    id = xcd_remap(id, T);
    const int y = id / 12;
    const int n0 = (id % 12) * 256;
    const int* mboff = bases + 8;
    const int e = (y >= mboff[1]) + (y >= mboff[2]) + (y >= mboff[3]);
    const int m0 = (y - mboff[e]) << 7;
    const int count = cnt[e];
    const int NK = DM / 32;   // 24

    __shared__ __align__(16) short As[3][4096];
    __shared__ __align__(16) short Bs[3][8192];

    const int tid = threadIdx.x;
    const int wave = tid >> 6, lane = tid & 63;
    const int wm = (wave & 1) * 64, wn = (wave >> 1) * 64;
    const int lrow = lane & 15;
    const int qg = lane >> 4;

    const int srow = tid >> 2;                              // 0..127
    const int qsrc = ((tid & 3) ^ ((tid >> 3) & 3)) * 8;    // source k-quad pre-swizzle
    int r0 = min(m0 + srow, count - 1);
    const ushort* a0 = Xb + (size_t)list[e * NTOK + r0] * DM + qsrc;
    const ushort* Wb = W1t + (size_t)e * DF * DM;
    const ushort* bp0 = Wb + (size_t)(n0 + srow) * DM + qsrc;
    const ushort* bp1 = bp0 + (size_t)128 * DM;

    int aOff[4], bOff[4];
#pragma unroll
    for (int i = 0; i < 4; ++i) {
        int ra = wm + i * 16 + lrow;
        aOff[i] = ra * 32 + (qg ^ ((ra >> 1) & 3)) * 8;
        int rb = wn + i * 16 + lrow;
        bOff[i] = rb * 32 + (qg ^ ((rb >> 1) & 3)) * 8;
    }

    f32x4 z = {0.f, 0.f, 0.f, 0.f};
    f32x4 acc[4][4];
#pragma unroll
    for (int i = 0; i < 4; ++i)
#pragma unroll
        for (int j = 0; j < 4; ++j) acc[i][j] = z;

    auto STAGE = [&](int wb) {
        cp16(a0, &As[wb][0] + tid * 8);
        cp16(bp0, &Bs[wb][0] + tid * 8);
        cp16(bp1, &Bs[wb][4096] + tid * 8);
        a0 += 32; bp0 += 32; bp1 += 32;
    };

    STAGE(0); STAGE(1);                         // depth-2 prologue, 6 cp16 in flight
    int rb = 0;
    for (int ks = 0; ks < NK; ++ks) {
        __builtin_amdgcn_sched_barrier(0);
        if (ks + 1 < NK) { asm volatile("s_waitcnt vmcnt(3)" ::: "memory"); }
        else             { asm volatile("s_waitcnt vmcnt(0)" ::: "memory"); }
        __builtin_amdgcn_s_barrier();
        __builtin_amdgcn_sched_barrier(0);
        if (ks + 2 < NK) {
            int wb = rb - 1; if (wb < 0) wb += 3;   // (ks+2)%3
            STAGE(wb);
        }
        const short* Ab = &As[rb][0];
        const short* Bb = &Bs[rb][0];
        bf16x8 av[4], bv[4];
#pragma unroll
        for (int i = 0; i < 4; ++i) av[i] = *(const bf16x8*)(Ab + aOff[i]);
#pragma unroll
        for (int j = 0; j < 4; ++j) bv[j] = *(const bf16x8*)(Bb + bOff[j]);
#pragma unroll
        for (int i = 0; i < 4; ++i)
#pragma unroll
            for (int j = 0; j < 4; ++j)
                acc[i][j] = __builtin_amdgcn_mfma_f32_16x16x32_bf16(av[i], bv[j], acc[i][j], 0, 0, 0);
        rb = (rb + 1 == 3) ? 0 : rb + 1;
    }

    const int base = bases[e];
    float bias[4];
#pragma unroll
    for (int j = 0; j < 4; ++j)
        bias[j] = b1[e * DF + n0 + wn + j * 16 + lrow];
#pragma unroll
    for (int i = 0; i < 4; ++i) {
        int gm = m0 + wm + i * 16 + qg * 4;
#pragma unroll
        for (int j = 0; j < 4; ++j) {
            int gn = n0 + wn + j * 16 + lrow;
#pragma unroll
            for (int r = 0; r < 4; ++r) {
                int row = gm + r;
                if (row < count) {
                    float v = acc[i][j][r] + bias[j];
                    h1[(size_t)(base + row) * DF + gn] = f2bf(fast_gelu(v));
                }
            }
        }
    }
}

__global__ __launch_bounds__(256, 3) void gemm2_kernel(
    const ushort* __restrict__ h1, const ushort* __restrict__ W2t,
    const float* __restrict__ b2, const int* __restrict__ cnt,
    const int* __restrict__ bases, ushort* __restrict__ h2) {
    const int mb = bases[12];
    const int T = mb * 6;
    int id = blockIdx.y * 6 + blockIdx.x;
    if (id >= T) return;
    id = xcd_remap(id, T);
    const int y = id / 6;
    const int n0 = (id % 6) * 128;
    const int* mboff = bases + 8;
    const int e = (y >= mboff[1]) + (y >= mboff[2]) + (y >= mboff[3]);
    const int m0 = (y - mboff[e]) << 7;
    const int count = cnt[e];
    const int base = bases[e];
    const int NK = DF / 32;   // 96

    __shared__ __align__(16) short As[3][4096];
    __shared__ __align__(16) short Bs[3][4096];

    const int tid = threadIdx.x;
    const int wave = tid >> 6, lane = tid & 63;
    const int wm = (wave & 1) * 64, wn = (wave >> 1) * 64;
    const int lrow = lane & 15;
    const int qg = lane >> 4;

    const int srow = tid >> 2;                              // 0..63
    const int qsrc = ((tid & 3) ^ ((tid >> 3) & 3)) * 8;
    int r0 = min(m0 + srow, count - 1);
    int r1 = min(m0 + 64 + srow, count - 1);
    const ushort* a0 = h1 + (size_t)(base + r0) * DF + qsrc;
    const ushort* a1 = h1 + (size_t)(base + r1) * DF + qsrc;
    const ushort* Wb = W2t + (size_t)e * DM * DF;
    const ushort* bp0 = Wb + (size_t)(n0 + srow) * DF + qsrc;
    const ushort* bp1 = bp0 + (size_t)64 * DF;

    int aOff[4], bOff[4];
#pragma unroll
    for (int i = 0; i < 4; ++i) {
        int ra = wm + i * 16 + lrow;
        aOff[i] = ra * 32 + (qg ^ ((ra >> 1) & 3)) * 8;
        int rbo = wn + i * 16 + lrow;
        bOff[i] = rbo * 32 + (qg ^ ((rbo >> 1) & 3)) * 8;
    }

    f32x4 z = {0.f, 0.f, 0.f, 0.f};
    f32x4 acc[4][4];
#pragma unroll
    for (int i = 0; i < 4; ++i)
#pragma unroll
        for (int j = 0; j < 4; ++j) acc[i][j] = z;

    auto STAGE = [&](int wb) {
        cp16(a0, &As[wb][0] + tid * 8);
        cp16(a1, &As[wb][2048] + tid * 8);
        cp16(bp0, &Bs[wb][0] + tid * 8);
        cp16(bp1, &Bs[wb][2048] + tid * 8);
        a0 += 32; a1 += 32; bp0 += 32; bp1 += 32;
    };

    STAGE(0); STAGE(1);                         // depth-2 prologue, 8 cp16 in flight
    int rb = 0;
    for (int ks = 0; ks < NK; ++ks) {
        __builtin_amdgcn_sched_barrier(0);
        if (ks + 1 < NK) { asm volatile("s_waitcnt vmcnt(4)" ::: "memory"); }
        else             { asm volatile("s_waitcnt vmcnt(0)" ::: "memory"); }
        __builtin_amdgcn_s_barrier();
        __builtin_amdgcn_sched_barrier(0);
        if (ks + 2 < NK) {
            int wb = rb - 1; if (wb < 0) wb += 3;
            STAGE(wb);
        }
        const short* Ab = &As[rb][0];
        const short* Bb = &Bs[rb][0];
        bf16x8 av[4], bv[4];
#pragma unroll
        for (int i = 0; i < 4; ++i) av[i] = *(const bf16x8*)(Ab + aOff[i]);
#pragma unroll
        for (int j = 0; j < 4; ++j) bv[j] = *(const bf16x8*)(Bb + bOff[j]);
#pragma unroll
        for (int i = 0; i < 4; ++i)
#pragma unroll
            for (int j = 0; j < 4; ++j)
                acc[i][j] = __builtin_amdgcn_mfma_f32_16x16x32_bf16(av[i], bv[j], acc[i][j], 0, 0, 0);
        rb = (rb + 1 == 3) ? 0 : rb + 1;
    }

    float bias[4];
#pragma unroll
    for (int j = 0; j < 4; ++j)
        bias[j] = b2[e * DM + n0 + wn + j * 16 + lrow];
#pragma unroll
    for (int i = 0; i < 4; ++i) {
        int gm = m0 + wm + i * 16 + qg * 4;
#pragma unroll
        for (int j = 0; j < 4; ++j) {
            int gn = n0 + wn + j * 16 + lrow;
#pragma unroll
            for (int r = 0; r < 4; ++r) {
                int row = gm + r;
                if (row < count)
                    h2[(size_t)(base + row) * DM + gn] = f2bf(acc[i][j][r] + bias[j]);
            }
        }
    }
}

// ---------------- finalize: 8 tokens/block, one WAVE per token ----------------
__global__ __launch_bounds__(256) void finalize_kernel(
    const float* __restrict__ X, const int* __restrict__ type_seq,
    const int* __restrict__ pos_of, const int* __restrict__ bases,
    const ushort* __restrict__ h2,
    const float* __restrict__ ln_g, const float* __restrict__ ln_b,
    const float* __restrict__ out_g, const float* __restrict__ out_b,
    float* __restrict__ out) {
    const int tid = threadIdx.x;
    const int wave = tid >> 6, lane = tid & 63;
    const int col0 = lane * 4;

#pragma unroll 1
    for (int ti = 0; ti < 2; ++ti) {
        const int t = blockIdx.x * 8 + wave * 2 + ti;
        const int k = type_seq[t];

        const float* Xr = X + (size_t)t * DM;
        float4 xv[3];
#pragma unroll
        for (int j = 0; j < 3; ++j) xv[j] = *(const float4*)(Xr + col0 + j * 256);

        float rv[12];
        if (k > 0) {
            const int e = k - 1;
            const size_t row = (size_t)(bases[e] + pos_of[t]);
            const ushort* hr = h2 + row * DM;
            float v[12];
            float s1 = 0.f, s2 = 0.f;
#pragma unroll
            for (int j = 0; j < 3; ++j) {
                ushort4 hv = *(const ushort4*)(hr + col0 + j * 256);
                float f0 = bf2f(hv.x) + xv[j].x;
                float f1 = bf2f(hv.y) + xv[j].y;
                float f2 = bf2f(hv.z) + xv[j].z;
                float f3 = bf2f(hv.w) + xv[j].w;
                v[j * 4 + 0] = f0; v[j * 4 + 1] = f1;
                v[j * 4 + 2] = f2; v[j * 4 + 3] = f3;
                s1 += (f0 + f1) + (f2 + f3);
                s2 += (f0 * f0 + f1 * f1) + (f2 * f2 + f3 * f3);
            }
#pragma unroll
            for (int off = 32; off > 0; off >>= 1) {
                s1 += __shfl_xor(s1, off, 64);
                s2 += __shfl_xor(s2, off, 64);
            }
            float m = s1 * (1.f / DM);
            float inv = rsqrtf(s2 * (1.f / DM) - m * m + 1e-12f);
#pragma unroll
            for (int j = 0; j < 3; ++j) {
                float4 g = *(const float4*)(ln_g + e * DM + col0 + j * 256);
                float4 b = *(const float4*)(ln_b + e * DM + col0 + j * 256);
                rv[j * 4 + 0] = (v[j * 4 + 0] - m) * inv * g.x + b.x;
                rv[j * 4 + 1] = (v[j * 4 + 1] - m) * inv * g.y + b.y;
                rv[j * 4 + 2] = (v[j * 4 + 2] - m) * inv * g.z + b.z;
                rv[j * 4 + 3] = (v[j * 4 + 3] - m) * inv * g.w + b.w;
            }
        } else {
#pragma unroll
            for (int j = 0; j < 12; ++j) rv[j] = 0.f;
        }

        float w[12];
        float s1 = 0.f, s2 = 0.f;
#pragma unroll
        for (int j = 0; j < 3; ++j) {
            float f0 = rv[j * 4 + 0] + xv[j].x;
            float f1 = rv[j * 4 + 1] + xv[j].y;
            float f2 = rv[j * 4 + 2] + xv[j].z;
            float f3 = rv[j * 4 + 3] + xv[j].w;
            w[j * 4 + 0] = f0; w[j * 4 + 1] = f1;
            w[j * 4 + 2] = f2; w[j * 4 + 3] = f3;
            s1 += (f0 + f1) + (f2 + f3);
            s2 += (f0 * f0 + f1 * f1) + (f2 * f2 + f3 * f3);
        }
#pragma unroll
        for (int off = 32; off > 0; off >>= 1) {
            s1 += __shfl_xor(s1, off, 64);
            s2 += __shfl_xor(s2, off, 64);
        }
        float m = s1 * (1.f / DM);
        float inv = rsqrtf(s2 * (1.f / DM) - m * m + 1e-12f);
#pragma unroll
        for (int j = 0; j < 3; ++j) {
            float4 g = *(const float4*)(out_g + col0 + j * 256);
            float4 b = *(const float4*)(out_b + col0 + j * 256);
            float4 o;
            o.x = (w[j * 4 + 0] - m) * inv * g.x + b.x;
            o.y = (w[j * 4 + 1] - m) * inv * g.y + b.y;
            o.z = (w[j * 4 + 2] - m) * inv * g.z + b.z;
            o.w = (w[j * 4 + 3] - m) * inv * g.w + b.w;
            *(float4*)(out + (size_t)t * DM + col0 + j * 256) = o;
        }
    }
}

// ---------------- launcher ----------------
extern "C" void kernel_launch(void* const* d_in, const int* in_sizes, int n_in,
                              void* d_out, int out_size, void* d_ws, size_t ws_size,
                              hipStream_t stream) {
    if (ws_size < (size_t)WS_END) return;

    const float* X     = (const float*)d_in[0];
    const int*   type  = (const int*)d_in[1];
    const float* W1    = (const float*)d_in[2];
    const float* b1    = (const float*)d_in[3];
    const float* W2    = (const float*)d_in[4];
    const float* b2    = (const float*)d_in[5];
    const float* ln_g  = (const float*)d_in[6];
    const float* ln_b  = (const float*)d_in[7];
    const float* out_g = (const float*)d_in[8];
    const float* out_b = (const float*)d_in[9];
    float* out = (float*)d_out;

    char* ws = (char*)d_ws;
    int* cnt    = (int*)(ws + WS_CNT);
    int* bases  = (int*)(ws + WS_BASES);
    int* pos_of = (int*)(ws + WS_POS);
    int* list   = (int*)(ws + WS_LIST);
    ushort* Xb  = (ushort*)(ws + WS_XB);
    ushort* W1t = (ushort*)(ws + WS_W1T);
    ushort* W2t = (ushort*)(ws + WS_W2T);
    ushort* h1  = (ushort*)(ws + WS_H1);
    ushort* h2  = (ushort*)(ws + WS_H2);

    hipMemsetAsync(cnt, 0, NEXP * sizeof(int), stream);   // routing counters
    prep_kernel<<<PREP_BLKS, 256, 0, stream>>>(type, X, W1, W2,
                                               cnt, pos_of, list, Xb, W1t, W2t);
    scan_kernel<<<1, 64, 0, stream>>>(cnt, bases);
    gemm1_kernel<<<dim3(12, 132), 512, 0, stream>>>(Xb, W1t, b1, cnt, bases, list, h1);
    gemm2_kernel<<<dim3(6, 132), 256, 0, stream>>>(h1, W2t, b2, cnt, bases, h2);
    finalize_kernel<<<NTOK / 8, 256, 0, stream>>>(X, type, pos_of, bases, h2, ln_g, ln_b, out_g, out_b, out);
}